// Round 1
// baseline (825.768 us; speedup 1.0000x reference)
//
#include <hip/hip_runtime.h>
#include <math.h>

#define NN 20000
#define EE 480000
#define GG 200

// ---------------------------------------------------------------------------
// Fold kernel: per-layer edge-attention collapses to a 4x4 matvec on edge_attr.
// fold layout (floats): [0..15]=M2(i*4+h) [16..19]=c2 [20..35]=M3 [36..39]=c3
//                       [40..43]=M4 [44]=c4
// ---------------------------------------------------------------------------
__global__ void fold_kernel(const float* __restrict__ We_enc, const float* __restrict__ be_enc,
                            const float* __restrict__ We2, const float* __restrict__ ae2,
                            const float* __restrict__ We3, const float* __restrict__ ae3,
                            const float* __restrict__ We4, const float* __restrict__ ae4,
                            float* __restrict__ fold) {
  __shared__ float V[32 * 4];
  int t = threadIdx.x;  // 128 threads
  // ---- layer 2: V2[k][h] = sum_c We2[k][h*32+c] * ae2[h][c]
  {
    int k = t >> 2, h = t & 3;
    float s = 0.f;
    for (int c = 0; c < 32; ++c) s = fmaf(We2[k * 128 + h * 32 + c], ae2[h * 32 + c], s);
    V[k * 4 + h] = s;
  }
  __syncthreads();
  if (t < 16) {
    int i = t >> 2, h = t & 3;
    float s = 0.f;
    for (int k = 0; k < 32; ++k) s = fmaf(We_enc[i * 32 + k], V[k * 4 + h], s);
    fold[i * 4 + h] = s;
  } else if (t < 20) {
    int h = t - 16;
    float s = 0.f;
    for (int k = 0; k < 32; ++k) s = fmaf(be_enc[k], V[k * 4 + h], s);
    fold[16 + h] = s;
  }
  __syncthreads();
  // ---- layer 3
  {
    int k = t >> 2, h = t & 3;
    float s = 0.f;
    for (int c = 0; c < 32; ++c) s = fmaf(We3[k * 128 + h * 32 + c], ae3[h * 32 + c], s);
    V[k * 4 + h] = s;
  }
  __syncthreads();
  if (t < 16) {
    int i = t >> 2, h = t & 3;
    float s = 0.f;
    for (int k = 0; k < 32; ++k) s = fmaf(We_enc[i * 32 + k], V[k * 4 + h], s);
    fold[20 + i * 4 + h] = s;
  } else if (t < 20) {
    int h = t - 16;
    float s = 0.f;
    for (int k = 0; k < 32; ++k) s = fmaf(be_enc[k], V[k * 4 + h], s);
    fold[36 + h] = s;
  }
  __syncthreads();
  // ---- layer 4 (heads=1): V4[k] = sum_c We4[k][c]*ae4[c]
  if (t < 32) {
    float s = 0.f;
    for (int c = 0; c < 32; ++c) s = fmaf(We4[t * 32 + c], ae4[c], s);
    V[t] = s;
  }
  __syncthreads();
  if (t < 4) {
    float s = 0.f;
    for (int k = 0; k < 32; ++k) s = fmaf(We_enc[t * 32 + k], V[k], s);
    fold[40 + t] = s;
  } else if (t == 4) {
    float s = 0.f;
    for (int k = 0; k < 32; ++k) s = fmaf(be_enc[k], V[k], s);
    fold[44] = s;
  }
}

// ---------------------------------------------------------------------------
// CSR build: histogram by dst, exclusive scan, scatter (+fold edge alphas)
// ---------------------------------------------------------------------------
__global__ void hist_kernel(const int* __restrict__ dst, int* __restrict__ cnt) {
  int i = blockIdx.x * 256 + threadIdx.x;
  if (i < EE) atomicAdd(&cnt[dst[i]], 1);
}

__global__ void scan_kernel(const int* __restrict__ cnt, int* __restrict__ row_ptr) {
  __shared__ int buf[1024];
  int carry = 0;
  if (threadIdx.x == 0) row_ptr[0] = 0;
  for (int base = 0; base < NN; base += 1024) {
    int i = base + (int)threadIdx.x;
    int v = (i < NN) ? cnt[i] : 0;
    buf[threadIdx.x] = v;
    __syncthreads();
    for (int offd = 1; offd < 1024; offd <<= 1) {
      int tmp = (threadIdx.x >= (unsigned)offd) ? buf[threadIdx.x - offd] : 0;
      __syncthreads();
      buf[threadIdx.x] += tmp;
      __syncthreads();
    }
    if (i < NN) row_ptr[i + 1] = carry + buf[threadIdx.x];
    carry += buf[1023];
    __syncthreads();
  }
}

__global__ void scatter_kernel(const int* __restrict__ src, const int* __restrict__ dst,
                               const float* __restrict__ attr, const int* __restrict__ row_ptr,
                               int* __restrict__ pos, const float* __restrict__ fold,
                               int* __restrict__ csr_src, float* __restrict__ cae2,
                               float* __restrict__ cae3, float* __restrict__ cae4) {
  int e = blockIdx.x * 256 + threadIdx.x;
  if (e >= EE) return;
  int d = dst[e];
  int p = row_ptr[d] + atomicAdd(&pos[d], 1);
  csr_src[p] = src[e];
  float a0 = attr[e * 4 + 0], a1 = attr[e * 4 + 1], a2 = attr[e * 4 + 2], a3 = attr[e * 4 + 3];
#pragma unroll
  for (int h = 0; h < 4; ++h) {
    cae2[p * 4 + h] = fold[16 + h] + a0 * fold[0 + h] + a1 * fold[4 + h] + a2 * fold[8 + h] + a3 * fold[12 + h];
    cae3[p * 4 + h] = fold[36 + h] + a0 * fold[20 + h] + a1 * fold[24 + h] + a2 * fold[28 + h] + a3 * fold[32 + h];
  }
  cae4[p] = fold[44] + a0 * fold[40] + a1 * fold[41] + a2 * fold[42] + a3 * fold[43];
}

// per-node mean of per-edge alpha_e -> self-loop alpha_e (linearity of the fold)
__global__ void loopae_kernel(const int* __restrict__ row_ptr, const float* __restrict__ cae2,
                              const float* __restrict__ cae3, const float* __restrict__ cae4,
                              float* __restrict__ l2, float* __restrict__ l3, float* __restrict__ l4) {
  int t = blockIdx.x * 256 + threadIdx.x;
  if (t >= NN * 4) return;
  int nid = t >> 2, h = t & 3;
  int p0 = row_ptr[nid], p1 = row_ptr[nid + 1];
  int deg = p1 - p0;
  float inv = 1.f / (float)(deg > 1 ? deg : 1);
  float s2 = 0.f, s3 = 0.f, s4 = 0.f;
  for (int p = p0; p < p1; ++p) {
    s2 += cae2[p * 4 + h];
    s3 += cae3[p * 4 + h];
    if (h == 0) s4 += cae4[p];
  }
  l2[t] = s2 * inv;
  l3[t] = s3 * inv;
  if (h == 0) l4[nid] = s4 * inv;
}

// ---------------------------------------------------------------------------
// Node GEMM: H = X @ W  (no bias), fused a_s/a_d head reductions.
// Block = 128 threads, 8 rows/block. COLS=128 (4 heads) or 32 (1 head).
// ---------------------------------------------------------------------------
template <int K, int HEADS>
__global__ void gemm_att_kernel(const float* __restrict__ X, const float* __restrict__ W,
                                const float* __restrict__ att_s, const float* __restrict__ att_d,
                                float* __restrict__ H, float* __restrict__ a_s,
                                float* __restrict__ a_d) {
  constexpr int COLS = HEADS * 32;
  constexpr int RPI = 128 / COLS;   // rows in parallel per iter
  constexpr int ROWS = 8;           // rows per block (NN % 8 == 0)
  constexpr int RPT = ROWS / RPI;   // rows per thread
  __shared__ float xs[ROWS][K];
  int tid = threadIdx.x;
  int row0 = blockIdx.x * ROWS;
  for (int idx = tid; idx < ROWS * K; idx += 128) {
    int r = idx / K, k = idx % K;
    xs[r][k] = X[(row0 + r) * K + k];
  }
  __syncthreads();
  int c = tid % COLS;
  int rp = tid / COLS;
  float acc[RPT];
#pragma unroll
  for (int j = 0; j < RPT; ++j) acc[j] = 0.f;
  for (int k = 0; k < K; ++k) {
    float wv = W[k * COLS + c];
#pragma unroll
    for (int j = 0; j < RPT; ++j) acc[j] = fmaf(xs[rp + j * RPI][k], wv, acc[j]);
  }
  float asv = att_s[c], adv = att_d[c];  // att_s is [H,32] contiguous == att_s[c]
#pragma unroll
  for (int j = 0; j < RPT; ++j) {
    int row = row0 + rp + j * RPI;
    float vs = acc[j] * asv, vd = acc[j] * adv;
#pragma unroll
    for (int m = 16; m >= 1; m >>= 1) {
      vs += __shfl_xor(vs, m);
      vd += __shfl_xor(vd, m);
    }
    H[row * COLS + c] = acc[j];
    if ((tid & 31) == 0) {
      a_s[row * HEADS + (c >> 5)] = vs;
      a_d[row * HEADS + (c >> 5)] = vd;
    }
  }
}

// ---------------------------------------------------------------------------
// GAT aggregation: per-node edge softmax + weighted gather. Thread=channel,
// 32-lane group = head; two passes (max, then exp/sum/acc); self-loop included.
// ---------------------------------------------------------------------------
template <int HEADS, bool RELU, bool HAS_EDGE>
__global__ void gat_agg_kernel(const float* __restrict__ Hh, const float* __restrict__ a_s,
                               const float* __restrict__ a_d, const float* __restrict__ cae,
                               const float* __restrict__ lae, const int* __restrict__ row_ptr,
                               const int* __restrict__ csr_src, const float* __restrict__ bias,
                               float* __restrict__ out) {
  constexpr int COLS = HEADS * 32;
  constexpr int NPB = 128 / COLS;
  int tid = threadIdx.x;
  int node = blockIdx.x * NPB + tid / COLS;
  if (node >= NN) return;
  int c = tid % COLS;
  int h = c >> 5;
  int p0 = row_ptr[node], p1 = row_ptr[node + 1];
  float adv = a_d[node * HEADS + h];
  float al = a_s[node * HEADS + h] + adv + (HAS_EDGE ? lae[node * HEADS + h] : 0.f);
  al = al >= 0.f ? al : 0.2f * al;
  float m = al;
  for (int p = p0; p < p1; ++p) {
    int s = csr_src[p];
    float a = a_s[s * HEADS + h] + adv + (HAS_EDGE ? cae[p * HEADS + h] : 0.f);
    a = a >= 0.f ? a : 0.2f * a;
    m = fmaxf(m, a);
  }
  float e0 = expf(al - m);
  float den = e0;
  float acc = e0 * Hh[node * COLS + c];
  for (int p = p0; p < p1; ++p) {
    int s = csr_src[p];
    float a = a_s[s * HEADS + h] + adv + (HAS_EDGE ? cae[p * HEADS + h] : 0.f);
    a = a >= 0.f ? a : 0.2f * a;
    float ex = expf(a - m);
    den += ex;
    acc = fmaf(ex, Hh[s * COLS + c], acc);
  }
  float o = acc / (den + 1e-16f) + bias[c];
  if (RELU) o = fmaxf(o, 0.f);
  out[node * COLS + c] = o;
}

// ---------------------------------------------------------------------------
// Global mean pool + descriptor MLP + final linear + sigmoid
// ---------------------------------------------------------------------------
__global__ void pool_kernel(const float* __restrict__ h4, const int* __restrict__ batch,
                            float* __restrict__ g_sum, float* __restrict__ g_cnt) {
  int i = blockIdx.x * 256 + threadIdx.x;
  if (i >= NN * 32) return;
  int nid = i >> 5, c = i & 31;
  int g = batch[nid];
  atomicAdd(&g_sum[g * 32 + c], h4[i]);
  if (c == 0) atomicAdd(&g_cnt[g], 1.f);
}

__global__ void final_kernel(const float* __restrict__ g_sum, const float* __restrict__ g_cnt,
                             const float* __restrict__ desc, const float* __restrict__ Wd,
                             const float* __restrict__ bd, const float* __restrict__ Wl,
                             const float* __restrict__ bl, float* __restrict__ outp) {
  int wid = (blockIdx.x * blockDim.x + threadIdx.x) >> 6;
  int lane = threadIdx.x & 63;
  if (wid >= GG) return;
  float v;
  if (lane < 32) {
    float cntv = g_cnt[wid];
    cntv = cntv > 1.f ? cntv : 1.f;
    v = (g_sum[wid * 32 + lane] / cntv) * Wl[lane];
  } else {
    int c = lane - 32;
    float acc = bd[c];
    for (int k = 0; k < 48; ++k) acc = fmaf(desc[wid * 48 + k], Wd[k * 32 + c], acc);
    v = fmaxf(acc, 0.f) * Wl[32 + c];
  }
#pragma unroll
  for (int m = 32; m >= 1; m >>= 1) v += __shfl_xor(v, m);
  if (lane == 0) outp[wid] = 1.f / (1.f + expf(-(v + bl[0])));
}

// ---------------------------------------------------------------------------
extern "C" void kernel_launch(void* const* d_in, const int* in_sizes, int n_in,
                              void* d_out, int out_size, void* d_ws, size_t ws_size,
                              hipStream_t stream) {
  const float* x = (const float*)d_in[0];
  const int* ei = (const int*)d_in[1];
  const float* edge_attr = (const float*)d_in[2];
  const int* batch = (const int*)d_in[3];
  const float* desc = (const float*)d_in[4];
  const float* We_enc = (const float*)d_in[5];
  const float* be_enc = (const float*)d_in[6];
  const float* W1 = (const float*)d_in[7];
  const float* as1 = (const float*)d_in[8];
  const float* ad1 = (const float*)d_in[9];
  const float* b1 = (const float*)d_in[10];
  const float* W2 = (const float*)d_in[11];
  const float* We2 = (const float*)d_in[12];
  const float* as2 = (const float*)d_in[13];
  const float* ad2 = (const float*)d_in[14];
  const float* ae2 = (const float*)d_in[15];
  const float* b2 = (const float*)d_in[16];
  const float* W3 = (const float*)d_in[17];
  const float* We3 = (const float*)d_in[18];
  const float* as3 = (const float*)d_in[19];
  const float* ad3 = (const float*)d_in[20];
  const float* ae3 = (const float*)d_in[21];
  const float* b3 = (const float*)d_in[22];
  const float* W4 = (const float*)d_in[23];
  const float* We4 = (const float*)d_in[24];
  const float* as4 = (const float*)d_in[25];
  const float* ad4 = (const float*)d_in[26];
  const float* ae4 = (const float*)d_in[27];
  const float* b4 = (const float*)d_in[28];
  const float* Wd = (const float*)d_in[29];
  const float* bd = (const float*)d_in[30];
  const float* Wl = (const float*)d_in[31];
  const float* bl = (const float*)d_in[32];

  const int* srcp = ei;
  const int* dstp = ei + EE;

  char* w = (char*)d_ws;
  size_t off = 0;
  auto take = [&](size_t nbytes) -> void* {
    void* p = (void*)(w + off);
    off += (nbytes + 255) & ~(size_t)255;
    return p;
  };
  int* cnt = (int*)take(NN * 4);            // doubles as scatter `pos`
  int* row_ptr = (int*)take((NN + 1) * 4);
  int* csr_src = (int*)take((size_t)EE * 4);
  float* cae2 = (float*)take((size_t)EE * 16);
  float* cae3 = (float*)take((size_t)EE * 16);
  float* cae4 = (float*)take((size_t)EE * 4);
  float* l2 = (float*)take(NN * 16);
  float* l3 = (float*)take(NN * 16);
  float* l4 = (float*)take(NN * 4);
  float* fold = (float*)take(48 * 4);
  float* a_s = (float*)take(NN * 16);
  float* a_d = (float*)take(NN * 16);
  float* hbuf = (float*)take((size_t)NN * 128 * 4);
  float* obuf = (float*)take((size_t)NN * 128 * 4);
  float* g_sum = (float*)take(GG * 32 * 4);
  float* g_cnt = (float*)take(GG * 4);
  (void)ws_size;

  // ---- CSR build + folded edge alphas
  hipMemsetAsync(cnt, 0, NN * 4, stream);
  hist_kernel<<<(EE + 255) / 256, 256, 0, stream>>>(dstp, cnt);
  scan_kernel<<<1, 1024, 0, stream>>>(cnt, row_ptr);
  hipMemsetAsync(cnt, 0, NN * 4, stream);
  fold_kernel<<<1, 128, 0, stream>>>(We_enc, be_enc, We2, ae2, We3, ae3, We4, ae4, fold);
  scatter_kernel<<<(EE + 255) / 256, 256, 0, stream>>>(srcp, dstp, edge_attr, row_ptr, cnt, fold,
                                                       csr_src, cae2, cae3, cae4);
  loopae_kernel<<<(NN * 4 + 255) / 256, 256, 0, stream>>>(row_ptr, cae2, cae3, cae4, l2, l3, l4);

  // ---- layer 1 (8 -> 4x32, no edge feats)
  gemm_att_kernel<8, 4><<<NN / 8, 128, 0, stream>>>(x, W1, as1, ad1, hbuf, a_s, a_d);
  gat_agg_kernel<4, true, false><<<NN, 128, 0, stream>>>(hbuf, a_s, a_d, nullptr, nullptr, row_ptr,
                                                         csr_src, b1, obuf);
  // ---- layer 2
  gemm_att_kernel<128, 4><<<NN / 8, 128, 0, stream>>>(obuf, W2, as2, ad2, hbuf, a_s, a_d);
  gat_agg_kernel<4, true, true><<<NN, 128, 0, stream>>>(hbuf, a_s, a_d, cae2, l2, row_ptr, csr_src,
                                                        b2, obuf);
  // ---- layer 3
  gemm_att_kernel<128, 4><<<NN / 8, 128, 0, stream>>>(obuf, W3, as3, ad3, hbuf, a_s, a_d);
  gat_agg_kernel<4, true, true><<<NN, 128, 0, stream>>>(hbuf, a_s, a_d, cae3, l3, row_ptr, csr_src,
                                                        b3, obuf);
  // ---- layer 4 (128 -> 32, heads=1, no relu)
  gemm_att_kernel<128, 1><<<NN / 8, 128, 0, stream>>>(obuf, W4, as4, ad4, hbuf, a_s, a_d);
  gat_agg_kernel<1, false, true><<<NN / 4, 128, 0, stream>>>(hbuf, a_s, a_d, cae4, l4, row_ptr,
                                                             csr_src, b4, obuf);

  // ---- pool + head
  hipMemsetAsync(g_sum, 0, GG * 32 * 4, stream);
  hipMemsetAsync(g_cnt, 0, GG * 4, stream);
  pool_kernel<<<(NN * 32 + 255) / 256, 256, 0, stream>>>(obuf, batch, g_sum, g_cnt);
  final_kernel<<<(GG + 3) / 4, 256, 0, stream>>>(g_sum, g_cnt, desc, Wd, bd, Wl, bl,
                                                 (float*)d_out);
}

// Round 2
// 457.101 us; speedup vs baseline: 1.8065x; 1.8065x over previous
//
#include <hip/hip_runtime.h>
#include <hip/hip_bf16.h>
#include <math.h>

#define NN 20000
#define EE 480000
#define GG 200

// ---------------------------------------------------------------------------
// Fold kernel: per-layer edge-attention collapses to a 4x4 matvec on edge_attr.
// fold layout (floats): [0..15]=M2(i*4+h) [16..19]=c2 [20..35]=M3 [36..39]=c3
//                       [40..43]=M4 [44]=c4
// ---------------------------------------------------------------------------
__global__ void fold_kernel(const float* __restrict__ We_enc, const float* __restrict__ be_enc,
                            const float* __restrict__ We2, const float* __restrict__ ae2,
                            const float* __restrict__ We3, const float* __restrict__ ae3,
                            const float* __restrict__ We4, const float* __restrict__ ae4,
                            float* __restrict__ fold) {
  __shared__ float V[32 * 4];
  int t = threadIdx.x;  // 128 threads
  {
    int k = t >> 2, h = t & 3;
    float s = 0.f;
    for (int c = 0; c < 32; ++c) s = fmaf(We2[k * 128 + h * 32 + c], ae2[h * 32 + c], s);
    V[k * 4 + h] = s;
  }
  __syncthreads();
  if (t < 16) {
    int i = t >> 2, h = t & 3;
    float s = 0.f;
    for (int k = 0; k < 32; ++k) s = fmaf(We_enc[i * 32 + k], V[k * 4 + h], s);
    fold[i * 4 + h] = s;
  } else if (t < 20) {
    int h = t - 16;
    float s = 0.f;
    for (int k = 0; k < 32; ++k) s = fmaf(be_enc[k], V[k * 4 + h], s);
    fold[16 + h] = s;
  }
  __syncthreads();
  {
    int k = t >> 2, h = t & 3;
    float s = 0.f;
    for (int c = 0; c < 32; ++c) s = fmaf(We3[k * 128 + h * 32 + c], ae3[h * 32 + c], s);
    V[k * 4 + h] = s;
  }
  __syncthreads();
  if (t < 16) {
    int i = t >> 2, h = t & 3;
    float s = 0.f;
    for (int k = 0; k < 32; ++k) s = fmaf(We_enc[i * 32 + k], V[k * 4 + h], s);
    fold[20 + i * 4 + h] = s;
  } else if (t < 20) {
    int h = t - 16;
    float s = 0.f;
    for (int k = 0; k < 32; ++k) s = fmaf(be_enc[k], V[k * 4 + h], s);
    fold[36 + h] = s;
  }
  __syncthreads();
  if (t < 32) {
    float s = 0.f;
    for (int c = 0; c < 32; ++c) s = fmaf(We4[t * 32 + c], ae4[c], s);
    V[t] = s;
  }
  __syncthreads();
  if (t < 4) {
    float s = 0.f;
    for (int k = 0; k < 32; ++k) s = fmaf(We_enc[t * 32 + k], V[k], s);
    fold[40 + t] = s;
  } else if (t == 4) {
    float s = 0.f;
    for (int k = 0; k < 32; ++k) s = fmaf(be_enc[k], V[k], s);
    fold[44] = s;
  }
}

// ---------------------------------------------------------------------------
// CSR build: histogram by dst, multi-block scan, scatter (+fold edge alphas)
// ---------------------------------------------------------------------------
__global__ void hist_kernel(const int* __restrict__ dst, int* __restrict__ cnt) {
  int i = blockIdx.x * 256 + threadIdx.x;
  if (i < EE) atomicAdd(&cnt[dst[i]], 1);
}

__global__ void scan1_kernel(const int* __restrict__ cnt, int* __restrict__ row_ptr,
                             int* __restrict__ partial) {
  __shared__ int buf[1024];
  int t = threadIdx.x;
  int i = blockIdx.x * 1024 + t;
  int v = (i < NN) ? cnt[i] : 0;
  buf[t] = v;
  __syncthreads();
  for (int offd = 1; offd < 1024; offd <<= 1) {
    int tmp = (t >= offd) ? buf[t - offd] : 0;
    __syncthreads();
    buf[t] += tmp;
    __syncthreads();
  }
  if (i < NN) row_ptr[i + 1] = buf[t];  // inclusive within block
  if (t == 1023) partial[blockIdx.x] = buf[1023];
}

__global__ void scan2_kernel(int* __restrict__ partial, int nblk) {
  int t = threadIdx.x;  // 64 threads, one wave
  int v = (t < nblk) ? partial[t] : 0;
  for (int offd = 1; offd < 32; offd <<= 1) {
    int u = __shfl_up(v, offd);
    if (t >= offd) v += u;
  }
  if (t < nblk) partial[t] = v;  // inclusive
}

__global__ void scan3_kernel(int* __restrict__ row_ptr, const int* __restrict__ partial) {
  int i = blockIdx.x * 256 + threadIdx.x;
  if (i == 0) row_ptr[0] = 0;
  if (i >= 1 && i <= NN) {
    int b = (i - 1) >> 10;
    if (b > 0) row_ptr[i] += partial[b - 1];
  }
}

__global__ void scatter_kernel(const int* __restrict__ src, const int* __restrict__ dst,
                               const float* __restrict__ attr, const int* __restrict__ row_ptr,
                               int* __restrict__ pos, const float* __restrict__ fold,
                               int* __restrict__ csr_src, float* __restrict__ cae2,
                               float* __restrict__ cae3, float* __restrict__ cae4) {
  int e = blockIdx.x * 256 + threadIdx.x;
  if (e >= EE) return;
  int d = dst[e];
  int p = row_ptr[d] + atomicAdd(&pos[d], 1);
  csr_src[p] = src[e];
  float a0 = attr[e * 4 + 0], a1 = attr[e * 4 + 1], a2 = attr[e * 4 + 2], a3 = attr[e * 4 + 3];
#pragma unroll
  for (int h = 0; h < 4; ++h) {
    cae2[p * 4 + h] = fold[16 + h] + a0 * fold[0 + h] + a1 * fold[4 + h] + a2 * fold[8 + h] + a3 * fold[12 + h];
    cae3[p * 4 + h] = fold[36 + h] + a0 * fold[20 + h] + a1 * fold[24 + h] + a2 * fold[28 + h] + a3 * fold[32 + h];
  }
  cae4[p] = fold[44] + a0 * fold[40] + a1 * fold[41] + a2 * fold[42] + a3 * fold[43];
}

// per-node mean of per-edge alpha_e -> self-loop alpha_e (linearity of the fold)
__global__ void loopae_kernel(const int* __restrict__ row_ptr, const float* __restrict__ cae2,
                              const float* __restrict__ cae3, const float* __restrict__ cae4,
                              float* __restrict__ l2, float* __restrict__ l3, float* __restrict__ l4) {
  int t = blockIdx.x * 256 + threadIdx.x;
  if (t >= NN * 4) return;
  int nid = t >> 2, h = t & 3;
  int p0 = row_ptr[nid], p1 = row_ptr[nid + 1];
  int deg = p1 - p0;
  float inv = 1.f / (float)(deg > 1 ? deg : 1);
  float s2 = 0.f, s3 = 0.f, s4 = 0.f;
  for (int p = p0; p < p1; ++p) {
    s2 += cae2[p * 4 + h];
    s3 += cae3[p * 4 + h];
    if (h == 0) s4 += cae4[p];
  }
  l2[t] = s2 * inv;
  l3[t] = s3 * inv;
  if (h == 0) l4[nid] = s4 * inv;
}

// ---------------------------------------------------------------------------
// Node GEMM: H = X @ W (no bias), bf16 H output, fused a_s/a_d head reductions.
// ---------------------------------------------------------------------------
template <int K, int HEADS>
__global__ void gemm_att_kernel(const float* __restrict__ X, const float* __restrict__ W,
                                const float* __restrict__ att_s, const float* __restrict__ att_d,
                                __hip_bfloat16* __restrict__ H, float* __restrict__ a_s,
                                float* __restrict__ a_d) {
  constexpr int COLS = HEADS * 32;
  constexpr int RPI = 128 / COLS;
  constexpr int ROWS = 8;
  constexpr int RPT = ROWS / RPI;
  __shared__ float xs[ROWS][K];
  int tid = threadIdx.x;
  int row0 = blockIdx.x * ROWS;
  for (int idx = tid; idx < ROWS * K; idx += 128) {
    int r = idx / K, k = idx % K;
    xs[r][k] = X[(row0 + r) * K + k];
  }
  __syncthreads();
  int c = tid % COLS;
  int rp = tid / COLS;
  float acc[RPT];
#pragma unroll
  for (int j = 0; j < RPT; ++j) acc[j] = 0.f;
  for (int k = 0; k < K; ++k) {
    float wv = W[k * COLS + c];
#pragma unroll
    for (int j = 0; j < RPT; ++j) acc[j] = fmaf(xs[rp + j * RPI][k], wv, acc[j]);
  }
  float asv = att_s[c], adv = att_d[c];
#pragma unroll
  for (int j = 0; j < RPT; ++j) {
    int row = row0 + rp + j * RPI;
    float vs = acc[j] * asv, vd = acc[j] * adv;
#pragma unroll
    for (int m = 16; m >= 1; m >>= 1) {
      vs += __shfl_xor(vs, m);
      vd += __shfl_xor(vd, m);
    }
    H[row * COLS + c] = __float2bfloat16(acc[j]);
    if ((tid & 31) == 0) {
      a_s[row * HEADS + (c >> 5)] = vs;
      a_d[row * HEADS + (c >> 5)] = vd;
    }
  }
}

// ---------------------------------------------------------------------------
// GAT aggregation v2: per-(edge,head) alpha computed ONCE, softmax weights in
// LDS, then a single bf16 gather pass. Block = 128 threads, group = COLS
// threads per node. EPP = COLS/HEADS = 32 edges per pass.
// ---------------------------------------------------------------------------
#define CAP 160  // max degree on the fast path (true max deg ~55)

template <int HEADS, bool RELU, bool HAS_EDGE>
__global__ void gat_agg2_kernel(const __hip_bfloat16* __restrict__ Hh,
                                const float* __restrict__ a_s, const float* __restrict__ a_d,
                                const float* __restrict__ cae, const float* __restrict__ lae,
                                const int* __restrict__ row_ptr, const int* __restrict__ csr_src,
                                const float* __restrict__ bias, float* __restrict__ out) {
  constexpr int COLS = HEADS * 32;
  constexpr int NPB = 128 / COLS;   // nodes per block
  constexpr int EPP = COLS / HEADS; // 32 edges per pass
  constexpr int JMAX = CAP / EPP;   // 5 register slots

  __shared__ float ex_lds[NPB][CAP * HEADS];
  __shared__ int src_lds[NPB][CAP];
  __shared__ float redm[2][4], redd[2][4];
  __shared__ float hdr_exl[4], hdr_den[4];

  int tid = threadIdx.x;
  int nl = tid / COLS;          // node within block
  int g = tid % COLS;           // lane within group
  int node = blockIdx.x * NPB + nl;
  if (node >= NN) return;
  int p0 = row_ptr[node], p1 = row_ptr[node + 1];
  int deg = p1 - p0;

  if (deg > CAP) {
    // ---- slow fallback (never taken for this input; formal correctness) ----
    int c = g;
    int hF = (HEADS == 4) ? (c >> 5) : 0;
    float adv = a_d[node * HEADS + hF];
    float al = a_s[node * HEADS + hF] + adv + (HAS_EDGE ? lae[node * HEADS + hF] : 0.f);
    al = al >= 0.f ? al : 0.2f * al;
    float m = al;
    for (int p = p0; p < p1; ++p) {
      int s = csr_src[p];
      float a = a_s[s * HEADS + hF] + adv + (HAS_EDGE ? cae[p * HEADS + hF] : 0.f);
      a = a >= 0.f ? a : 0.2f * a;
      m = fmaxf(m, a);
    }
    float e0 = __expf(al - m);
    float den = e0;
    float acc = e0 * __bfloat162float(Hh[node * COLS + c]);
    for (int p = p0; p < p1; ++p) {
      int s = csr_src[p];
      float a = a_s[s * HEADS + hF] + adv + (HAS_EDGE ? cae[p * HEADS + hF] : 0.f);
      a = a >= 0.f ? a : 0.2f * a;
      float ex = __expf(a - m);
      den += ex;
      acc = fmaf(ex, __bfloat162float(Hh[s * COLS + c]), acc);
    }
    float o = acc / (den + 1e-16f) + bias[c];
    if (RELU) o = fmaxf(o, 0.f);
    out[node * COLS + c] = o;
    return;
  }

  int p_rel = g / HEADS;  // 0..31
  int h = g % HEADS;
  float adv = a_d[node * HEADS + h];

  // ---- Phase A: alphas (once per edge-head), src stash, running max
  float areg[JMAX];
  float mpart = -1e30f;
#pragma unroll
  for (int j = 0; j < JMAX; ++j) {
    int pr = p_rel + j * EPP;
    areg[j] = -1e30f;
    if (pr < deg) {
      int p = p0 + pr;
      int s = csr_src[p];
      if (h == 0) src_lds[nl][pr] = s;
      float a = a_s[s * HEADS + h] + adv;
      if (HAS_EDGE) a += cae[p * HEADS + h];
      a = a >= 0.f ? a : 0.2f * a;
      areg[j] = a;
      mpart = fmaxf(mpart, a);
    }
  }
  float al = 0.f;
  if (p_rel == 0) {
    al = a_s[node * HEADS + h] + adv + (HAS_EDGE ? lae[node * HEADS + h] : 0.f);
    al = al >= 0.f ? al : 0.2f * al;
    mpart = fmaxf(mpart, al);
  }
  // reduce max over same-h lanes
  float mfull;
  if constexpr (COLS == 128) {
#pragma unroll
    for (int m = 4; m <= 32; m <<= 1) mpart = fmaxf(mpart, __shfl_xor(mpart, m));
    if ((tid & 63) < 4) redm[tid >> 6][tid & 3] = mpart;
    __syncthreads();
    mfull = fmaxf(redm[0][h], redm[1][h]);
  } else {
#pragma unroll
    for (int m = 1; m <= 16; m <<= 1) mpart = fmaxf(mpart, __shfl_xor(mpart, m));
    mfull = mpart;
  }

  // ---- Phase B: exp, weights to LDS, denominator
  float dpart = 0.f;
#pragma unroll
  for (int j = 0; j < JMAX; ++j) {
    int pr = p_rel + j * EPP;
    if (pr < deg) {
      float ex = __expf(areg[j] - mfull);
      ex_lds[nl][pr * HEADS + h] = ex;
      dpart += ex;
    }
  }
  float exl = 0.f;
  if (p_rel == 0) {
    exl = __expf(al - mfull);
    dpart += exl;
  }
  float den;
  if constexpr (COLS == 128) {
#pragma unroll
    for (int m = 4; m <= 32; m <<= 1) dpart += __shfl_xor(dpart, m);
    if ((tid & 63) < 4) redd[tid >> 6][tid & 3] = dpart;
    __syncthreads();
    den = redd[0][h] + redd[1][h];
    if (g < 4) {
      hdr_exl[h] = exl;
      hdr_den[h] = den;
    }
    __syncthreads();
  } else {
#pragma unroll
    for (int m = 1; m <= 16; m <<= 1) dpart += __shfl_xor(dpart, m);
    den = dpart;
    exl = __shfl(exl, tid & 32);  // broadcast from group base lane
  }

  // ---- Phase C: weighted bf16 gather
  int c = g;
  float exl_c, den_c;
  if constexpr (COLS == 128) {
    int hC = c >> 5;
    exl_c = hdr_exl[hC];
    den_c = hdr_den[hC];
  } else {
    exl_c = exl;
    den_c = den;
  }
  int hC = (HEADS == 4) ? (c >> 5) : 0;
  float acc = exl_c * __bfloat162float(Hh[node * COLS + c]);
#pragma unroll 4
  for (int p = 0; p < deg; ++p) {
    int s = src_lds[nl][p];
    float ex = ex_lds[nl][p * HEADS + hC];
    acc = fmaf(ex, __bfloat162float(Hh[s * COLS + c]), acc);
  }
  float o = acc / (den_c + 1e-16f) + bias[c];
  if (RELU) o = fmaxf(o, 0.f);
  out[node * COLS + c] = o;
}

// ---------------------------------------------------------------------------
// Global mean pool + descriptor MLP + final linear + sigmoid
// ---------------------------------------------------------------------------
__global__ void pool_kernel(const float* __restrict__ h4, const int* __restrict__ batch,
                            float* __restrict__ g_sum, float* __restrict__ g_cnt) {
  int i = blockIdx.x * 256 + threadIdx.x;
  if (i >= NN * 32) return;
  int nid = i >> 5, c = i & 31;
  int g = batch[nid];
  atomicAdd(&g_sum[g * 32 + c], h4[i]);
  if (c == 0) atomicAdd(&g_cnt[g], 1.f);
}

__global__ void final_kernel(const float* __restrict__ g_sum, const float* __restrict__ g_cnt,
                             const float* __restrict__ desc, const float* __restrict__ Wd,
                             const float* __restrict__ bd, const float* __restrict__ Wl,
                             const float* __restrict__ bl, float* __restrict__ outp) {
  int wid = (blockIdx.x * blockDim.x + threadIdx.x) >> 6;
  int lane = threadIdx.x & 63;
  if (wid >= GG) return;
  float v;
  if (lane < 32) {
    float cntv = g_cnt[wid];
    cntv = cntv > 1.f ? cntv : 1.f;
    v = (g_sum[wid * 32 + lane] / cntv) * Wl[lane];
  } else {
    int c = lane - 32;
    float acc = bd[c];
    for (int k = 0; k < 48; ++k) acc = fmaf(desc[wid * 48 + k], Wd[k * 32 + c], acc);
    v = fmaxf(acc, 0.f) * Wl[32 + c];
  }
#pragma unroll
  for (int m = 32; m >= 1; m >>= 1) v += __shfl_xor(v, m);
  if (lane == 0) outp[wid] = 1.f / (1.f + expf(-(v + bl[0])));
}

// ---------------------------------------------------------------------------
extern "C" void kernel_launch(void* const* d_in, const int* in_sizes, int n_in,
                              void* d_out, int out_size, void* d_ws, size_t ws_size,
                              hipStream_t stream) {
  const float* x = (const float*)d_in[0];
  const int* ei = (const int*)d_in[1];
  const float* edge_attr = (const float*)d_in[2];
  const int* batch = (const int*)d_in[3];
  const float* desc = (const float*)d_in[4];
  const float* We_enc = (const float*)d_in[5];
  const float* be_enc = (const float*)d_in[6];
  const float* W1 = (const float*)d_in[7];
  const float* as1 = (const float*)d_in[8];
  const float* ad1 = (const float*)d_in[9];
  const float* b1 = (const float*)d_in[10];
  const float* W2 = (const float*)d_in[11];
  const float* We2 = (const float*)d_in[12];
  const float* as2 = (const float*)d_in[13];
  const float* ad2 = (const float*)d_in[14];
  const float* ae2 = (const float*)d_in[15];
  const float* b2 = (const float*)d_in[16];
  const float* W3 = (const float*)d_in[17];
  const float* We3 = (const float*)d_in[18];
  const float* as3 = (const float*)d_in[19];
  const float* ad3 = (const float*)d_in[20];
  const float* ae3 = (const float*)d_in[21];
  const float* b3 = (const float*)d_in[22];
  const float* W4 = (const float*)d_in[23];
  const float* We4 = (const float*)d_in[24];
  const float* as4 = (const float*)d_in[25];
  const float* ad4 = (const float*)d_in[26];
  const float* ae4 = (const float*)d_in[27];
  const float* b4 = (const float*)d_in[28];
  const float* Wd = (const float*)d_in[29];
  const float* bd = (const float*)d_in[30];
  const float* Wl = (const float*)d_in[31];
  const float* bl = (const float*)d_in[32];

  const int* srcp = ei;
  const int* dstp = ei + EE;

  char* w = (char*)d_ws;
  size_t off = 0;
  auto take = [&](size_t nbytes) -> void* {
    void* p = (void*)(w + off);
    off += (nbytes + 255) & ~(size_t)255;
    return p;
  };
  int* cnt = (int*)take(NN * 4);  // doubles as scatter `pos`
  int* row_ptr = (int*)take((NN + 1) * 4);
  int* csr_src = (int*)take((size_t)EE * 4);
  float* cae2 = (float*)take((size_t)EE * 16);
  float* cae3 = (float*)take((size_t)EE * 16);
  float* cae4 = (float*)take((size_t)EE * 4);
  float* l2 = (float*)take(NN * 16);
  float* l3 = (float*)take(NN * 16);
  float* l4 = (float*)take(NN * 4);
  float* fold = (float*)take(48 * 4);
  int* partial = (int*)take(64 * 4);
  float* a_s = (float*)take(NN * 16);
  float* a_d = (float*)take(NN * 16);
  __hip_bfloat16* hbuf = (__hip_bfloat16*)take((size_t)NN * 128 * 2);
  float* obuf = (float*)take((size_t)NN * 128 * 4);
  float* g_sum = (float*)take(GG * 32 * 4);
  float* g_cnt = (float*)take(GG * 4);
  (void)ws_size;

  constexpr int NSCAN = (NN + 1023) / 1024;  // 20

  // ---- CSR build + folded edge alphas
  hipMemsetAsync(cnt, 0, NN * 4, stream);
  hist_kernel<<<(EE + 255) / 256, 256, 0, stream>>>(dstp, cnt);
  scan1_kernel<<<NSCAN, 1024, 0, stream>>>(cnt, row_ptr, partial);
  scan2_kernel<<<1, 64, 0, stream>>>(partial, NSCAN);
  scan3_kernel<<<(NN + 256) / 256, 256, 0, stream>>>(row_ptr, partial);
  hipMemsetAsync(cnt, 0, NN * 4, stream);
  fold_kernel<<<1, 128, 0, stream>>>(We_enc, be_enc, We2, ae2, We3, ae3, We4, ae4, fold);
  scatter_kernel<<<(EE + 255) / 256, 256, 0, stream>>>(srcp, dstp, edge_attr, row_ptr, cnt, fold,
                                                       csr_src, cae2, cae3, cae4);
  loopae_kernel<<<(NN * 4 + 255) / 256, 256, 0, stream>>>(row_ptr, cae2, cae3, cae4, l2, l3, l4);

  // ---- layer 1 (8 -> 4x32, no edge feats)
  gemm_att_kernel<8, 4><<<NN / 8, 128, 0, stream>>>(x, W1, as1, ad1, hbuf, a_s, a_d);
  gat_agg2_kernel<4, true, false><<<NN, 128, 0, stream>>>(hbuf, a_s, a_d, nullptr, nullptr,
                                                          row_ptr, csr_src, b1, obuf);
  // ---- layer 2
  gemm_att_kernel<128, 4><<<NN / 8, 128, 0, stream>>>(obuf, W2, as2, ad2, hbuf, a_s, a_d);
  gat_agg2_kernel<4, true, true><<<NN, 128, 0, stream>>>(hbuf, a_s, a_d, cae2, l2, row_ptr,
                                                         csr_src, b2, obuf);
  // ---- layer 3
  gemm_att_kernel<128, 4><<<NN / 8, 128, 0, stream>>>(obuf, W3, as3, ad3, hbuf, a_s, a_d);
  gat_agg2_kernel<4, true, true><<<NN, 128, 0, stream>>>(hbuf, a_s, a_d, cae3, l3, row_ptr,
                                                         csr_src, b3, obuf);
  // ---- layer 4 (128 -> 32, heads=1, no relu)
  gemm_att_kernel<128, 1><<<NN / 8, 128, 0, stream>>>(obuf, W4, as4, ad4, hbuf, a_s, a_d);
  gat_agg2_kernel<1, false, true><<<(NN + 3) / 4, 128, 0, stream>>>(hbuf, a_s, a_d, cae4, l4,
                                                                    row_ptr, csr_src, b4, obuf);

  // ---- pool + head
  hipMemsetAsync(g_sum, 0, GG * 32 * 4, stream);
  hipMemsetAsync(g_cnt, 0, GG * 4, stream);
  pool_kernel<<<(NN * 32 + 255) / 256, 256, 0, stream>>>(obuf, batch, g_sum, g_cnt);
  final_kernel<<<(GG + 3) / 4, 256, 0, stream>>>(g_sum, g_cnt, desc, Wd, bd, Wl, bl,
                                                 (float*)d_out);
}

// Round 5
// 427.359 us; speedup vs baseline: 1.9323x; 1.0696x over previous
//
#include <hip/hip_runtime.h>
#include <hip/hip_bf16.h>
#include <math.h>

#define NN 20000
#define EE 480000
#define GG 200
#define CAP 96  // fast-path max degree (true max deg ~55); fallback is correct anyway

typedef unsigned int uint32;

static __device__ inline unsigned short f2bf(float f) {
  __hip_bfloat16 h = __float2bfloat16(f);
  return *reinterpret_cast<const unsigned short*>(&h);
}
static __device__ inline float bf2f(unsigned short u) {
  return __uint_as_float(((uint32)u) << 16);
}
static __device__ inline float bf_lo(uint32 u) { return __uint_as_float(u << 16); }
static __device__ inline float bf_hi(uint32 u) { return __uint_as_float(u & 0xffff0000u); }

// ---------------------------------------------------------------------------
// Fold kernel: per-layer edge-attention collapses to a 4x4 matvec on edge_attr.
// fold layout (floats): [0..15]=M2(i*4+h) [16..19]=c2 [20..35]=M3 [36..39]=c3
//                       [40..43]=M4 [44]=c4
// ---------------------------------------------------------------------------
__global__ void fold_kernel(const float* __restrict__ We_enc, const float* __restrict__ be_enc,
                            const float* __restrict__ We2, const float* __restrict__ ae2,
                            const float* __restrict__ We3, const float* __restrict__ ae3,
                            const float* __restrict__ We4, const float* __restrict__ ae4,
                            float* __restrict__ fold) {
  __shared__ float V[32 * 4];
  int t = threadIdx.x;  // 128 threads
  {
    int k = t >> 2, h = t & 3;
    float s = 0.f;
    for (int c = 0; c < 32; ++c) s = fmaf(We2[k * 128 + h * 32 + c], ae2[h * 32 + c], s);
    V[k * 4 + h] = s;
  }
  __syncthreads();
  if (t < 16) {
    int i = t >> 2, h = t & 3;
    float s = 0.f;
    for (int k = 0; k < 32; ++k) s = fmaf(We_enc[i * 32 + k], V[k * 4 + h], s);
    fold[i * 4 + h] = s;
  } else if (t < 20) {
    int h = t - 16;
    float s = 0.f;
    for (int k = 0; k < 32; ++k) s = fmaf(be_enc[k], V[k * 4 + h], s);
    fold[16 + h] = s;
  }
  __syncthreads();
  {
    int k = t >> 2, h = t & 3;
    float s = 0.f;
    for (int c = 0; c < 32; ++c) s = fmaf(We3[k * 128 + h * 32 + c], ae3[h * 32 + c], s);
    V[k * 4 + h] = s;
  }
  __syncthreads();
  if (t < 16) {
    int i = t >> 2, h = t & 3;
    float s = 0.f;
    for (int k = 0; k < 32; ++k) s = fmaf(We_enc[i * 32 + k], V[k * 4 + h], s);
    fold[20 + i * 4 + h] = s;
  } else if (t < 20) {
    int h = t - 16;
    float s = 0.f;
    for (int k = 0; k < 32; ++k) s = fmaf(be_enc[k], V[k * 4 + h], s);
    fold[36 + h] = s;
  }
  __syncthreads();
  if (t < 32) {
    float s = 0.f;
    for (int c = 0; c < 32; ++c) s = fmaf(We4[t * 32 + c], ae4[c], s);
    V[t] = s;
  }
  __syncthreads();
  if (t < 4) {
    float s = 0.f;
    for (int k = 0; k < 32; ++k) s = fmaf(We_enc[t * 32 + k], V[k], s);
    fold[40 + t] = s;
  } else if (t == 4) {
    float s = 0.f;
    for (int k = 0; k < 32; ++k) s = fmaf(be_enc[k], V[k], s);
    fold[44] = s;
  }
}

// ---------------------------------------------------------------------------
// CSR build: histogram by dst, multi-block scan, scatter (+fold edge alphas)
// ---------------------------------------------------------------------------
__global__ void hist_kernel(const int* __restrict__ dst, int* __restrict__ cnt) {
  int i = blockIdx.x * 256 + threadIdx.x;
  if (i < EE) atomicAdd(&cnt[dst[i]], 1);
}

__global__ void scan1_kernel(const int* __restrict__ cnt, int* __restrict__ row_ptr,
                             int* __restrict__ partial) {
  __shared__ int buf[1024];
  int t = threadIdx.x;
  int i = blockIdx.x * 1024 + t;
  int v = (i < NN) ? cnt[i] : 0;
  buf[t] = v;
  __syncthreads();
  for (int offd = 1; offd < 1024; offd <<= 1) {
    int tmp = (t >= offd) ? buf[t - offd] : 0;
    __syncthreads();
    buf[t] += tmp;
    __syncthreads();
  }
  if (i < NN) row_ptr[i + 1] = buf[t];  // inclusive within block
  if (t == 1023) partial[blockIdx.x] = buf[1023];
}

__global__ void scan2_kernel(int* __restrict__ partial, int nblk) {
  int t = threadIdx.x;  // 64 threads, one wave
  int v = (t < nblk) ? partial[t] : 0;
  for (int offd = 1; offd < 32; offd <<= 1) {
    int u = __shfl_up(v, offd);
    if (t >= offd) v += u;
  }
  if (t < nblk) partial[t] = v;  // inclusive
}

__global__ void scan3_kernel(int* __restrict__ row_ptr, const int* __restrict__ partial) {
  int i = blockIdx.x * 256 + threadIdx.x;
  if (i == 0) row_ptr[0] = 0;
  if (i >= 1 && i <= NN) {
    int b = (i - 1) >> 10;
    if (b > 0) row_ptr[i] += partial[b - 1];
  }
}

__global__ void scatter_kernel(const int* __restrict__ src, const int* __restrict__ dst,
                               const float* __restrict__ attr, const int* __restrict__ row_ptr,
                               int* __restrict__ pos, const float* __restrict__ fold,
                               int* __restrict__ csr_src, float* __restrict__ cae2,
                               float* __restrict__ cae3, float* __restrict__ cae4) {
  int e = blockIdx.x * 256 + threadIdx.x;
  if (e >= EE) return;
  int d = dst[e];
  int p = row_ptr[d] + atomicAdd(&pos[d], 1);
  csr_src[p] = src[e];
  float a0 = attr[e * 4 + 0], a1 = attr[e * 4 + 1], a2 = attr[e * 4 + 2], a3 = attr[e * 4 + 3];
#pragma unroll
  for (int h = 0; h < 4; ++h) {
    cae2[p * 4 + h] = fold[16 + h] + a0 * fold[0 + h] + a1 * fold[4 + h] + a2 * fold[8 + h] + a3 * fold[12 + h];
    cae3[p * 4 + h] = fold[36 + h] + a0 * fold[20 + h] + a1 * fold[24 + h] + a2 * fold[28 + h] + a3 * fold[32 + h];
  }
  cae4[p] = fold[44] + a0 * fold[40] + a1 * fold[41] + a2 * fold[42] + a3 * fold[43];
}

// per-node mean of per-edge alpha_e -> self-loop alpha_e (linearity of the fold)
__global__ void loopae_kernel(const int* __restrict__ row_ptr, const float* __restrict__ cae2,
                              const float* __restrict__ cae3, const float* __restrict__ cae4,
                              float* __restrict__ l2, float* __restrict__ l3, float* __restrict__ l4) {
  int t = blockIdx.x * 256 + threadIdx.x;
  if (t >= NN * 4) return;
  int nid = t >> 2, h = t & 3;
  int p0 = row_ptr[nid], p1 = row_ptr[nid + 1];
  int deg = p1 - p0;
  float inv = 1.f / (float)(deg > 1 ? deg : 1);
  float s2 = 0.f, s3 = 0.f, s4 = 0.f;
  for (int p = p0; p < p1; ++p) {
    s2 += cae2[p * 4 + h];
    s3 += cae3[p * 4 + h];
    if (h == 0) s4 += cae4[p];
  }
  l2[t] = s2 * inv;
  l3[t] = s3 * inv;
  if (h == 0) l4[nid] = s4 * inv;
}

// ---------------------------------------------------------------------------
// Node GEMM v1 (layer 1, K=8): H = X @ W, bf16 H, fused a_s/a_d reductions.
// ---------------------------------------------------------------------------
__global__ void gemm1_kernel(const float* __restrict__ X, const float* __restrict__ W,
                             const float* __restrict__ att_s, const float* __restrict__ att_d,
                             __hip_bfloat16* __restrict__ H, float* __restrict__ a_s,
                             float* __restrict__ a_d) {
  constexpr int K = 8;
  constexpr int COLS = 128;
  constexpr int ROWS = 8;
  __shared__ float xs[ROWS][K];
  int tid = threadIdx.x;
  int row0 = blockIdx.x * ROWS;
  if (tid < ROWS * K) xs[tid / K][tid % K] = X[row0 * K + tid];
  __syncthreads();
  int c = tid;  // 128 threads = 128 cols
  float acc[ROWS];
#pragma unroll
  for (int j = 0; j < ROWS; ++j) acc[j] = 0.f;
  for (int k = 0; k < K; ++k) {
    float wv = W[k * COLS + c];
#pragma unroll
    for (int j = 0; j < ROWS; ++j) acc[j] = fmaf(xs[j][k], wv, acc[j]);
  }
  float asv = att_s[c], adv = att_d[c];
#pragma unroll
  for (int j = 0; j < ROWS; ++j) {
    int row = row0 + j;
    float vs = acc[j] * asv, vd = acc[j] * adv;
#pragma unroll
    for (int m = 16; m >= 1; m >>= 1) {
      vs += __shfl_xor(vs, m);
      vd += __shfl_xor(vd, m);
    }
    H[row * COLS + c] = __float2bfloat16(acc[j]);
    if ((tid & 31) == 0) {
      a_s[row * 4 + (c >> 5)] = vs;
      a_d[row * 4 + (c >> 5)] = vd;
    }
  }
}

// ---------------------------------------------------------------------------
// Node GEMM v2 (K=128): register-tiled TRx4, W staged in LDS as bf16,
// X tile fp32 in LDS, b128/b64 LDS reads. Fused a_s/a_d head reductions.
// ---------------------------------------------------------------------------
template <int COLS, int TR>
__global__ __launch_bounds__(256) void gemm2_kernel(const float* __restrict__ X,
                                                    const float* __restrict__ W,
                                                    const float* __restrict__ att_s,
                                                    const float* __restrict__ att_d,
                                                    __hip_bfloat16* __restrict__ H,
                                                    float* __restrict__ a_s,
                                                    float* __restrict__ a_d) {
  constexpr int K = 128;
  constexpr int HEADS = COLS / 32;
  constexpr int CG = COLS / 4;   // col-groups (4 cols each)
  constexpr int RG = 256 / CG;   // row-groups
  constexpr int ROWS = RG * TR;  // rows per block
  __shared__ unsigned short ws[K * COLS];  // bf16 bits, [k][c]
  __shared__ float xs[ROWS * K];           // [r][k]
  int tid = threadIdx.x;
  int row0 = blockIdx.x * ROWS;
  // stage W -> bf16 LDS
  for (int i = tid * 4; i < K * COLS; i += 1024) {
    float4 wv = *(const float4*)&W[i];
    ushort4 u;
    u.x = f2bf(wv.x); u.y = f2bf(wv.y); u.z = f2bf(wv.z); u.w = f2bf(wv.w);
    *(ushort4*)&ws[i] = u;
  }
  // stage X tile (guarded, zero-fill)
  for (int i = tid * 4; i < ROWS * K; i += 1024) {
    int grow = row0 + i / K;
    float4 v = make_float4(0.f, 0.f, 0.f, 0.f);
    if (grow < NN) v = *(const float4*)&X[(size_t)grow * K + (i & (K - 1))];
    *(float4*)&xs[i] = v;
  }
  __syncthreads();
  int cg = tid % CG, rg = tid / CG;
  int c0 = cg * 4, r0 = rg * TR;
  float acc[TR][4];
#pragma unroll
  for (int i = 0; i < TR; ++i)
#pragma unroll
    for (int j = 0; j < 4; ++j) acc[i][j] = 0.f;
  for (int k0 = 0; k0 < K; k0 += 4) {
    float w4[4][4];
#pragma unroll
    for (int j = 0; j < 4; ++j) {  // j = k offset
      ushort4 u = *(ushort4*)&ws[(k0 + j) * COLS + c0];
      w4[j][0] = bf2f(u.x); w4[j][1] = bf2f(u.y); w4[j][2] = bf2f(u.z); w4[j][3] = bf2f(u.w);
    }
#pragma unroll
    for (int i = 0; i < TR; ++i) {
      float4 xv = *(float4*)&xs[(r0 + i) * K + k0];
#pragma unroll
      for (int j = 0; j < 4; ++j) {
        acc[i][j] = fmaf(xv.x, w4[0][j], acc[i][j]);
        acc[i][j] = fmaf(xv.y, w4[1][j], acc[i][j]);
        acc[i][j] = fmaf(xv.z, w4[2][j], acc[i][j]);
        acc[i][j] = fmaf(xv.w, w4[3][j], acc[i][j]);
      }
    }
  }
  float as4[4], ad4[4];
#pragma unroll
  for (int j = 0; j < 4; ++j) { as4[j] = att_s[c0 + j]; ad4[j] = att_d[c0 + j]; }
  int h = c0 >> 5;
#pragma unroll
  for (int i = 0; i < TR; ++i) {
    int row = row0 + r0 + i;
    ushort4 hv;
    hv.x = f2bf(acc[i][0]); hv.y = f2bf(acc[i][1]); hv.z = f2bf(acc[i][2]); hv.w = f2bf(acc[i][3]);
    if (row < NN) *(ushort4*)&H[(size_t)row * COLS + c0] = hv;
    float vs = 0.f, vd = 0.f;
#pragma unroll
    for (int j = 0; j < 4; ++j) {
      vs = fmaf(acc[i][j], as4[j], vs);
      vd = fmaf(acc[i][j], ad4[j], vd);
    }
#pragma unroll
    for (int m = 1; m <= 4; m <<= 1) {
      vs += __shfl_xor(vs, m);
      vd += __shfl_xor(vd, m);
    }
    if ((tid & 7) == 0 && row < NN) {
      a_s[row * HEADS + h] = vs;
      a_d[row * HEADS + h] = vd;
    }
  }
}

// ---------------------------------------------------------------------------
// GAT aggregation v3: all-shuffle, zero LDS. One node = NL lanes (NL=COLS/2),
// each lane owns 2 channels (one uint = 2 bf16). Alphas/exps/src in registers,
// distributed via __shfl. EPP=16 edges per register slot.
// ---------------------------------------------------------------------------
template <int HEADS, bool RELU, bool HAS_EDGE>
__global__ void gat_agg3_kernel(const __hip_bfloat16* __restrict__ Hh,
                                const float* __restrict__ a_s, const float* __restrict__ a_d,
                                const float* __restrict__ cae, const float* __restrict__ lae,
                                const int* __restrict__ row_ptr, const int* __restrict__ csr_src,
                                const float* __restrict__ bias, float* __restrict__ out) {
  constexpr int COLS = HEADS * 32;
  constexpr int NL = COLS / 2;     // lanes per node: 64 (H=4) or 16 (H=1)
  constexpr int NPB = 128 / NL;    // nodes per block: 2 or 8
  constexpr int EPP = NL / HEADS;  // 16 edges per register slot
  constexpr int JMAX = CAP / EPP;  // 6

  int tid = threadIdx.x;
  int nl = tid / NL;
  int ln = tid % NL;
  int node = blockIdx.x * NPB + nl;  // grids exact: NN%2==0, NN%8==0
  int p0 = row_ptr[node], p1 = row_ptr[node + 1];
  int deg = p1 - p0;
  int base = (tid & 63) & ~(NL - 1);  // node's base lane within wave
  const uint32* H32 = (const uint32*)Hh;
  int c = 2 * ln;
  int hc = c >> 5;

  if (deg <= CAP) {
    int p_rel = ln / HEADS;
    int h = ln % HEADS;
    float adv = a_d[node * HEADS + h];
    float av[JMAX];
    int sv[JMAX];
    float mpart = -1e30f;
#pragma unroll
    for (int j = 0; j < JMAX; ++j) {
      int pr = p_rel + j * EPP;
      av[j] = -1e30f;
      sv[j] = 0;
      if (pr < deg) {
        int p = p0 + pr;
        int s = csr_src[p];
        sv[j] = s;
        float a = a_s[s * HEADS + h] + adv;
        if (HAS_EDGE) a += cae[p * HEADS + h];
        a = a >= 0.f ? a : 0.2f * a;
        av[j] = a;
        mpart = fmaxf(mpart, a);
      }
    }
    float al = -1e30f;
    if (p_rel == 0) {
      al = a_s[node * HEADS + h] + adv + (HAS_EDGE ? lae[node * HEADS + h] : 0.f);
      al = al >= 0.f ? al : 0.2f * al;
      mpart = fmaxf(mpart, al);
    }
    float mfull = mpart;
#pragma unroll
    for (int m = HEADS; m < NL; m <<= 1) mfull = fmaxf(mfull, __shfl_xor(mfull, m));
    float dpart = 0.f;
#pragma unroll
    for (int j = 0; j < JMAX; ++j) {
      int pr = p_rel + j * EPP;
      if (pr < deg) {
        av[j] = __expf(av[j] - mfull);  // av now holds exp weight
        dpart += av[j];
      }
    }
    float exl = 0.f;
    if (p_rel == 0) {
      exl = __expf(al - mfull);
      dpart += exl;
    }
    float den = dpart;
#pragma unroll
    for (int m = HEADS; m < NL; m <<= 1) den += __shfl_xor(den, m);

    // Phase C: weighted gather, 2 bf16 channels per lane
    float exl_c = __shfl(exl, base + hc);
    float den_c = __shfl(den, base + hc);
    uint32 u0 = H32[(size_t)node * NL + ln];
    float acc0 = exl_c * bf_lo(u0);
    float acc1 = exl_c * bf_hi(u0);
#pragma unroll
    for (int j = 0; j < JMAX; ++j) {
      if (j * EPP < deg) {
#pragma unroll
        for (int pp = 0; pp < EPP; ++pp) {
          int p = j * EPP + pp;
          if (p < deg) {
            int srcl = base + pp * HEADS + hc;
            float ex = __shfl(av[j], srcl);
            int s = __shfl(sv[j], srcl);
            uint32 u = H32[(size_t)s * NL + ln];
            acc0 = fmaf(ex, bf_lo(u), acc0);
            acc1 = fmaf(ex, bf_hi(u), acc1);
          }
        }
      }
    }
    float inv = 1.f / (den_c + 1e-16f);
    float o0 = acc0 * inv + bias[c];
    float o1 = acc1 * inv + bias[c + 1];
    if (RELU) { o0 = fmaxf(o0, 0.f); o1 = fmaxf(o1, 0.f); }
    *(float2*)&out[(size_t)node * COLS + c] = make_float2(o0, o1);
  } else {
    // ---- slow fallback (never taken for this input; formal correctness) ----
    float adv = a_d[node * HEADS + hc];
    float al = a_s[node * HEADS + hc] + adv + (HAS_EDGE ? lae[node * HEADS + hc] : 0.f);
    al = al >= 0.f ? al : 0.2f * al;
    float m = al;
    for (int p = p0; p < p1; ++p) {
      int s = csr_src[p];
      float a = a_s[s * HEADS + hc] + adv + (HAS_EDGE ? cae[p * HEADS + hc] : 0.f);
      a = a >= 0.f ? a : 0.2f * a;
      m = fmaxf(m, a);
    }
    float e0 = __expf(al - m);
    float den = e0;
    uint32 u0 = H32[(size_t)node * NL + ln];
    float acc0 = e0 * bf_lo(u0), acc1 = e0 * bf_hi(u0);
    for (int p = p0; p < p1; ++p) {
      int s = csr_src[p];
      float a = a_s[s * HEADS + hc] + adv + (HAS_EDGE ? cae[p * HEADS + hc] : 0.f);
      a = a >= 0.f ? a : 0.2f * a;
      float ex = __expf(a - m);
      den += ex;
      uint32 u = H32[(size_t)s * NL + ln];
      acc0 = fmaf(ex, bf_lo(u), acc0);
      acc1 = fmaf(ex, bf_hi(u), acc1);
    }
    float inv = 1.f / (den + 1e-16f);
    float o0 = acc0 * inv + bias[c];
    float o1 = acc1 * inv + bias[c + 1];
    if (RELU) { o0 = fmaxf(o0, 0.f); o1 = fmaxf(o1, 0.f); }
    *(float2*)&out[(size_t)node * COLS + c] = make_float2(o0, o1);
  }
}

// ---------------------------------------------------------------------------
// Graph boundaries (batch is sorted) + fused mean-pool/descriptor-MLP/head
// ---------------------------------------------------------------------------
__global__ void bound_kernel(const int* __restrict__ batch, int* __restrict__ bound) {
  int i = blockIdx.x * 256 + threadIdx.x;
  if (i >= NN) return;
  int bc = batch[i];
  int bp = (i == 0) ? -1 : batch[i - 1];
  for (int g = bp + 1; g <= bc; ++g) bound[g] = i;
  if (i == NN - 1)
    for (int g = bc + 1; g <= GG; ++g) bound[g] = NN;
}

__global__ void pool_final_kernel(const float* __restrict__ h4, const int* __restrict__ bound,
                                  const float* __restrict__ desc, const float* __restrict__ Wd,
                                  const float* __restrict__ bd, const float* __restrict__ Wl,
                                  const float* __restrict__ bl, float* __restrict__ outp) {
  __shared__ float part[8][32];
  int g = blockIdx.x;
  int tid = threadIdx.x;  // 256
  int r0 = bound[g], r1 = bound[g + 1];
  int cch = tid & 31, chunk = tid >> 5;
  float s = 0.f;
  for (int r = r0 + chunk; r < r1; r += 8) s += h4[r * 32 + cch];
  part[chunk][cch] = s;
  __syncthreads();
  if (tid < 64) {
    float v;
    if (tid < 32) {
      float tot = 0.f;
#pragma unroll
      for (int k = 0; k < 8; ++k) tot += part[k][tid];
      int rows = r1 - r0;
      float cnt = (float)(rows > 1 ? rows : 1);
      v = (tot / cnt) * Wl[tid];
    } else {
      int cc = tid - 32;
      float acc = bd[cc];
      for (int k = 0; k < 48; ++k) acc = fmaf(desc[g * 48 + k], Wd[k * 32 + cc], acc);
      v = fmaxf(acc, 0.f) * Wl[32 + cc];
    }
#pragma unroll
    for (int m = 32; m >= 1; m >>= 1) v += __shfl_xor(v, m);
    if (tid == 0) outp[g] = 1.f / (1.f + expf(-(v + bl[0])));
  }
}

// ---------------------------------------------------------------------------
extern "C" void kernel_launch(void* const* d_in, const int* in_sizes, int n_in,
                              void* d_out, int out_size, void* d_ws, size_t ws_size,
                              hipStream_t stream) {
  const float* x = (const float*)d_in[0];
  const int* ei = (const int*)d_in[1];
  const float* edge_attr = (const float*)d_in[2];
  const int* batch = (const int*)d_in[3];
  const float* desc = (const float*)d_in[4];
  const float* We_enc = (const float*)d_in[5];
  const float* be_enc = (const float*)d_in[6];
  const float* W1 = (const float*)d_in[7];
  const float* as1 = (const float*)d_in[8];
  const float* ad1 = (const float*)d_in[9];
  const float* b1 = (const float*)d_in[10];
  const float* W2 = (const float*)d_in[11];
  const float* We2 = (const float*)d_in[12];
  const float* as2 = (const float*)d_in[13];
  const float* ad2 = (const float*)d_in[14];
  const float* ae2 = (const float*)d_in[15];
  const float* b2 = (const float*)d_in[16];
  const float* W3 = (const float*)d_in[17];
  const float* We3 = (const float*)d_in[18];
  const float* as3 = (const float*)d_in[19];
  const float* ad3 = (const float*)d_in[20];
  const float* ae3 = (const float*)d_in[21];
  const float* b3 = (const float*)d_in[22];
  const float* W4 = (const float*)d_in[23];
  const float* We4 = (const float*)d_in[24];
  const float* as4 = (const float*)d_in[25];
  const float* ad4 = (const float*)d_in[26];
  const float* ae4 = (const float*)d_in[27];
  const float* b4 = (const float*)d_in[28];
  const float* Wd = (const float*)d_in[29];
  const float* bd = (const float*)d_in[30];
  const float* Wl = (const float*)d_in[31];
  const float* bl = (const float*)d_in[32];

  const int* srcp = ei;
  const int* dstp = ei + EE;

  char* w = (char*)d_ws;
  size_t off = 0;
  auto take = [&](size_t nbytes) -> void* {
    void* p = (void*)(w + off);
    off += (nbytes + 255) & ~(size_t)255;
    return p;
  };
  int* cnt = (int*)take(NN * 4);  // doubles as scatter `pos`
  int* row_ptr = (int*)take((NN + 1) * 4);
  int* csr_src = (int*)take((size_t)EE * 4);
  float* cae2 = (float*)take((size_t)EE * 16);
  float* cae3 = (float*)take((size_t)EE * 16);
  float* cae4 = (float*)take((size_t)EE * 4);
  float* l2 = (float*)take(NN * 16);
  float* l3 = (float*)take(NN * 16);
  float* l4 = (float*)take(NN * 4);
  float* fold = (float*)take(48 * 4);
  int* partial = (int*)take(64 * 4);
  int* bound = (int*)take((GG + 1) * 4);
  float* a_s = (float*)take(NN * 16);
  float* a_d = (float*)take(NN * 16);
  __hip_bfloat16* hbuf = (__hip_bfloat16*)take((size_t)NN * 128 * 2);
  float* obuf = (float*)take((size_t)NN * 128 * 4);
  (void)ws_size;

  constexpr int NSCAN = (NN + 1023) / 1024;  // 20

  // ---- CSR build + folded edge alphas + graph bounds
  hipMemsetAsync(cnt, 0, NN * 4, stream);
  hist_kernel<<<(EE + 255) / 256, 256, 0, stream>>>(dstp, cnt);
  scan1_kernel<<<NSCAN, 1024, 0, stream>>>(cnt, row_ptr, partial);
  scan2_kernel<<<1, 64, 0, stream>>>(partial, NSCAN);
  scan3_kernel<<<(NN + 256) / 256, 256, 0, stream>>>(row_ptr, partial);
  hipMemsetAsync(cnt, 0, NN * 4, stream);
  fold_kernel<<<1, 128, 0, stream>>>(We_enc, be_enc, We2, ae2, We3, ae3, We4, ae4, fold);
  scatter_kernel<<<(EE + 255) / 256, 256, 0, stream>>>(srcp, dstp, edge_attr, row_ptr, cnt, fold,
                                                       csr_src, cae2, cae3, cae4);
  loopae_kernel<<<(NN * 4 + 255) / 256, 256, 0, stream>>>(row_ptr, cae2, cae3, cae4, l2, l3, l4);
  bound_kernel<<<(NN + 255) / 256, 256, 0, stream>>>(batch, bound);

  // ---- layer 1 (8 -> 4x32, no edge feats)
  gemm1_kernel<<<NN / 8, 128, 0, stream>>>(x, W1, as1, ad1, hbuf, a_s, a_d);
  gat_agg3_kernel<4, true, false><<<NN / 2, 128, 0, stream>>>(hbuf, a_s, a_d, nullptr, nullptr,
                                                              row_ptr, csr_src, b1, obuf);
  // ---- layer 2
  gemm2_kernel<128, 4><<<NN / 32, 256, 0, stream>>>(obuf, W2, as2, ad2, hbuf, a_s, a_d);
  gat_agg3_kernel<4, true, true><<<NN / 2, 128, 0, stream>>>(hbuf, a_s, a_d, cae2, l2, row_ptr,
                                                             csr_src, b2, obuf);
  // ---- layer 3
  gemm2_kernel<128, 4><<<NN / 32, 256, 0, stream>>>(obuf, W3, as3, ad3, hbuf, a_s, a_d);
  gat_agg3_kernel<4, true, true><<<NN / 2, 128, 0, stream>>>(hbuf, a_s, a_d, cae3, l3, row_ptr,
                                                             csr_src, b3, obuf);
  // ---- layer 4 (128 -> 32, heads=1, no relu)
  gemm2_kernel<32, 2><<<(NN + 63) / 64, 256, 0, stream>>>(obuf, W4, as4, ad4, hbuf, a_s, a_d);
  gat_agg3_kernel<1, false, true><<<NN / 8, 128, 0, stream>>>(hbuf, a_s, a_d, cae4, l4, row_ptr,
                                                              csr_src, b4, obuf);

  // ---- fused pool + descriptor MLP + final linear + sigmoid
  pool_final_kernel<<<GG, 256, 0, stream>>>(obuf, bound, desc, Wd, bd, Wl, bl, (float*)d_out);
}

// Round 7
// 353.816 us; speedup vs baseline: 2.3339x; 1.2079x over previous
//
#include <hip/hip_runtime.h>
#include <hip/hip_bf16.h>
#include <math.h>

#define NN 20000
#define EE 480000
#define GG 200
#define CAP 96  // fast-path max degree (true max deg ~55); fallback is correct anyway

typedef unsigned int uint32;

static __device__ inline unsigned short f2bf(float f) {
  __hip_bfloat16 h = __float2bfloat16(f);
  return *reinterpret_cast<const unsigned short*>(&h);
}
static __device__ inline float bf2f(unsigned short u) {
  return __uint_as_float(((uint32)u) << 16);
}
static __device__ inline float bf_lo(uint32 u) { return __uint_as_float(u << 16); }
static __device__ inline float bf_hi(uint32 u) { return __uint_as_float(u & 0xffff0000u); }

// ---------------------------------------------------------------------------
// Fold kernel: per-layer edge-attention collapses to a 4x4 matvec on edge_attr.
// fold layout (floats): [0..15]=M2(i*4+h) [16..19]=c2 [20..35]=M3 [36..39]=c3
//                       [40..43]=M4 [44]=c4
// ---------------------------------------------------------------------------
__global__ void fold_kernel(const float* __restrict__ We_enc, const float* __restrict__ be_enc,
                            const float* __restrict__ We2, const float* __restrict__ ae2,
                            const float* __restrict__ We3, const float* __restrict__ ae3,
                            const float* __restrict__ We4, const float* __restrict__ ae4,
                            float* __restrict__ fold) {
  __shared__ float V[32 * 4];
  int t = threadIdx.x;  // 128 threads
  {
    int k = t >> 2, h = t & 3;
    float s = 0.f;
    for (int c = 0; c < 32; ++c) s = fmaf(We2[k * 128 + h * 32 + c], ae2[h * 32 + c], s);
    V[k * 4 + h] = s;
  }
  __syncthreads();
  if (t < 16) {
    int i = t >> 2, h = t & 3;
    float s = 0.f;
    for (int k = 0; k < 32; ++k) s = fmaf(We_enc[i * 32 + k], V[k * 4 + h], s);
    fold[i * 4 + h] = s;
  } else if (t < 20) {
    int h = t - 16;
    float s = 0.f;
    for (int k = 0; k < 32; ++k) s = fmaf(be_enc[k], V[k * 4 + h], s);
    fold[16 + h] = s;
  }
  __syncthreads();
  {
    int k = t >> 2, h = t & 3;
    float s = 0.f;
    for (int c = 0; c < 32; ++c) s = fmaf(We3[k * 128 + h * 32 + c], ae3[h * 32 + c], s);
    V[k * 4 + h] = s;
  }
  __syncthreads();
  if (t < 16) {
    int i = t >> 2, h = t & 3;
    float s = 0.f;
    for (int k = 0; k < 32; ++k) s = fmaf(We_enc[i * 32 + k], V[k * 4 + h], s);
    fold[20 + i * 4 + h] = s;
  } else if (t < 20) {
    int h = t - 16;
    float s = 0.f;
    for (int k = 0; k < 32; ++k) s = fmaf(be_enc[k], V[k * 4 + h], s);
    fold[36 + h] = s;
  }
  __syncthreads();
  if (t < 32) {
    float s = 0.f;
    for (int c = 0; c < 32; ++c) s = fmaf(We4[t * 32 + c], ae4[c], s);
    V[t] = s;
  }
  __syncthreads();
  if (t < 4) {
    float s = 0.f;
    for (int k = 0; k < 32; ++k) s = fmaf(We_enc[t * 32 + k], V[k], s);
    fold[40 + t] = s;
  } else if (t == 4) {
    float s = 0.f;
    for (int k = 0; k < 32; ++k) s = fmaf(be_enc[k], V[k], s);
    fold[44] = s;
  }
}

// ---------------------------------------------------------------------------
// CSR build: histogram by dst, multi-block scan, scatter (src + edge_attr)
// ---------------------------------------------------------------------------
__global__ void hist_kernel(const int* __restrict__ dst, int* __restrict__ cnt) {
  int i = blockIdx.x * 256 + threadIdx.x;
  if (i < EE) atomicAdd(&cnt[dst[i]], 1);
}

__global__ void scan1_kernel(const int* __restrict__ cnt, int* __restrict__ row_ptr,
                             int* __restrict__ partial) {
  __shared__ int buf[1024];
  int t = threadIdx.x;
  int i = blockIdx.x * 1024 + t;
  int v = (i < NN) ? cnt[i] : 0;
  buf[t] = v;
  __syncthreads();
  for (int offd = 1; offd < 1024; offd <<= 1) {
    int tmp = (t >= offd) ? buf[t - offd] : 0;
    __syncthreads();
    buf[t] += tmp;
    __syncthreads();
  }
  if (i < NN) row_ptr[i + 1] = buf[t];  // inclusive within block
  if (t == 1023) partial[blockIdx.x] = buf[1023];
}

__global__ void scan2_kernel(int* __restrict__ partial, int nblk) {
  int t = threadIdx.x;  // 64 threads, one wave
  int v = (t < nblk) ? partial[t] : 0;
  for (int offd = 1; offd < 32; offd <<= 1) {
    int u = __shfl_up(v, offd);
    if (t >= offd) v += u;
  }
  if (t < nblk) partial[t] = v;  // inclusive
}

__global__ void scan3_kernel(int* __restrict__ row_ptr, const int* __restrict__ partial) {
  int i = blockIdx.x * 256 + threadIdx.x;
  if (i == 0) row_ptr[0] = 0;
  if (i >= 1 && i <= NN) {
    int b = (i - 1) >> 10;
    if (b > 0) row_ptr[i] += partial[b - 1];
  }
}

__global__ void scatter_kernel(const int* __restrict__ src, const int* __restrict__ dst,
                               const float* __restrict__ attr, const int* __restrict__ row_ptr,
                               int* __restrict__ pos, int* __restrict__ csr_src,
                               float* __restrict__ attr_csr) {
  int e = blockIdx.x * 256 + threadIdx.x;
  if (e >= EE) return;
  int d = dst[e];
  int p = row_ptr[d] + atomicAdd(&pos[d], 1);
  csr_src[p] = src[e];
  ((float4*)attr_csr)[p] = ((const float4*)attr)[e];
}

// per-node mean of edge_attr over incoming edges (coalesced CSR reads)
__global__ void attrmean_kernel(const int* __restrict__ row_ptr,
                                const float* __restrict__ attr_csr,
                                float* __restrict__ mean_attr) {
  int t = blockIdx.x * 256 + threadIdx.x;
  if (t >= NN * 4) return;
  int node = t >> 2, ch = t & 3;
  int p0 = row_ptr[node], p1 = row_ptr[node + 1];
  float s = 0.f;
  for (int p = p0; p < p1; ++p) s += attr_csr[p * 4 + ch];
  int deg = p1 - p0;
  mean_attr[t] = s / (float)(deg > 1 ? deg : 1);
}

// ---------------------------------------------------------------------------
// Node GEMM v1 (layer 1, K=8): H = X @ W, bf16 H, fused a_s/a_d reductions.
// ---------------------------------------------------------------------------
__global__ void gemm1_kernel(const float* __restrict__ X, const float* __restrict__ W,
                             const float* __restrict__ att_s, const float* __restrict__ att_d,
                             __hip_bfloat16* __restrict__ H, float* __restrict__ a_s,
                             float* __restrict__ a_d) {
  constexpr int K = 8;
  constexpr int COLS = 128;
  constexpr int ROWS = 8;
  __shared__ float xs[ROWS][K];
  int tid = threadIdx.x;
  int row0 = blockIdx.x * ROWS;
  if (tid < ROWS * K) xs[tid / K][tid % K] = X[row0 * K + tid];
  __syncthreads();
  int c = tid;  // 128 threads = 128 cols
  float acc[ROWS];
#pragma unroll
  for (int j = 0; j < ROWS; ++j) acc[j] = 0.f;
  for (int k = 0; k < K; ++k) {
    float wv = W[k * COLS + c];
#pragma unroll
    for (int j = 0; j < ROWS; ++j) acc[j] = fmaf(xs[j][k], wv, acc[j]);
  }
  float asv = att_s[c], adv = att_d[c];
#pragma unroll
  for (int j = 0; j < ROWS; ++j) {
    int row = row0 + j;
    float vs = acc[j] * asv, vd = acc[j] * adv;
#pragma unroll
    for (int m = 16; m >= 1; m >>= 1) {
      vs += __shfl_xor(vs, m);
      vd += __shfl_xor(vd, m);
    }
    H[row * COLS + c] = __float2bfloat16(acc[j]);
    if ((tid & 31) == 0) {
      a_s[row * 4 + (c >> 5)] = vs;
      a_d[row * 4 + (c >> 5)] = vd;
    }
  }
}

// ---------------------------------------------------------------------------
// Node GEMM v2 (K=128): register-tiled TRx4, W staged in LDS as bf16,
// X tile fp32 in LDS. Fused a_s/a_d head reductions.
// ---------------------------------------------------------------------------
template <int COLS, int TR>
__global__ __launch_bounds__(256) void gemm2_kernel(const float* __restrict__ X,
                                                    const float* __restrict__ W,
                                                    const float* __restrict__ att_s,
                                                    const float* __restrict__ att_d,
                                                    __hip_bfloat16* __restrict__ H,
                                                    float* __restrict__ a_s,
                                                    float* __restrict__ a_d) {
  constexpr int K = 128;
  constexpr int HEADS = COLS / 32;
  constexpr int CG = COLS / 4;   // col-groups (4 cols each)
  constexpr int RG = 256 / CG;   // row-groups
  constexpr int ROWS = RG * TR;  // rows per block
  __shared__ unsigned short ws[K * COLS];  // bf16 bits, [k][c]
  __shared__ float xs[ROWS * K];           // [r][k]
  int tid = threadIdx.x;
  int row0 = blockIdx.x * ROWS;
  // stage W -> bf16 LDS
  for (int i = tid * 4; i < K * COLS; i += 1024) {
    float4 wv = *(const float4*)&W[i];
    ushort4 u;
    u.x = f2bf(wv.x); u.y = f2bf(wv.y); u.z = f2bf(wv.z); u.w = f2bf(wv.w);
    *(ushort4*)&ws[i] = u;
  }
  // stage X tile (guarded, zero-fill)
  for (int i = tid * 4; i < ROWS * K; i += 1024) {
    int grow = row0 + i / K;
    float4 v = make_float4(0.f, 0.f, 0.f, 0.f);
    if (grow < NN) v = *(const float4*)&X[(size_t)grow * K + (i & (K - 1))];
    *(float4*)&xs[i] = v;
  }
  __syncthreads();
  int cg = tid % CG, rg = tid / CG;
  int c0 = cg * 4, r0 = rg * TR;
  float acc[TR][4];
#pragma unroll
  for (int i = 0; i < TR; ++i)
#pragma unroll
    for (int j = 0; j < 4; ++j) acc[i][j] = 0.f;
  for (int k0 = 0; k0 < K; k0 += 4) {
    float w4[4][4];
#pragma unroll
    for (int j = 0; j < 4; ++j) {  // j = k offset
      ushort4 u = *(ushort4*)&ws[(k0 + j) * COLS + c0];
      w4[j][0] = bf2f(u.x); w4[j][1] = bf2f(u.y); w4[j][2] = bf2f(u.z); w4[j][3] = bf2f(u.w);
    }
#pragma unroll
    for (int i = 0; i < TR; ++i) {
      float4 xv = *(float4*)&xs[(r0 + i) * K + k0];
#pragma unroll
      for (int j = 0; j < 4; ++j) {
        acc[i][j] = fmaf(xv.x, w4[0][j], acc[i][j]);
        acc[i][j] = fmaf(xv.y, w4[1][j], acc[i][j]);
        acc[i][j] = fmaf(xv.z, w4[2][j], acc[i][j]);
        acc[i][j] = fmaf(xv.w, w4[3][j], acc[i][j]);
      }
    }
  }
  float as4[4], ad4[4];
#pragma unroll
  for (int j = 0; j < 4; ++j) { as4[j] = att_s[c0 + j]; ad4[j] = att_d[c0 + j]; }
  int h = c0 >> 5;
#pragma unroll
  for (int i = 0; i < TR; ++i) {
    int row = row0 + r0 + i;
    ushort4 hv;
    hv.x = f2bf(acc[i][0]); hv.y = f2bf(acc[i][1]); hv.z = f2bf(acc[i][2]); hv.w = f2bf(acc[i][3]);
    if (row < NN) *(ushort4*)&H[(size_t)row * COLS + c0] = hv;
    float vs = 0.f, vd = 0.f;
#pragma unroll
    for (int j = 0; j < 4; ++j) {
      vs = fmaf(acc[i][j], as4[j], vs);
      vd = fmaf(acc[i][j], ad4[j], vd);
    }
#pragma unroll
    for (int m = 1; m <= 4; m <<= 1) {
      vs += __shfl_xor(vs, m);
      vd += __shfl_xor(vd, m);
    }
    if ((tid & 7) == 0 && row < NN) {
      a_s[row * HEADS + h] = vs;
      a_d[row * HEADS + h] = vd;
    }
  }
}

// ---------------------------------------------------------------------------
// GAT aggregation v4: all-shuffle, zero LDS, branchless softmax, edge alphas
// computed on the fly from attr_csr via the fold matvec. One node = NL lanes,
// each lane owns 2 channels. Phase C: all shfl extracts, then all 16 loads,
// then all fmas (no ds/vmem interleave).
// ---------------------------------------------------------------------------
template <int HEADS, bool RELU, bool HAS_EDGE>
__global__ __launch_bounds__(256) void gat_agg4_kernel(
    const __hip_bfloat16* __restrict__ Hh, const float* __restrict__ a_s,
    const float* __restrict__ a_d, const float* __restrict__ attr_csr,
    const float* __restrict__ mean_attr, const float* __restrict__ foldM,
    const float* __restrict__ foldC, const int* __restrict__ row_ptr,
    const int* __restrict__ csr_src, const float* __restrict__ bias,
    float* __restrict__ out) {
  constexpr int COLS = HEADS * 32;
  constexpr int NL = COLS / 2;     // lanes per node: 64 (H=4) or 16 (H=1)
  constexpr int NPB = 256 / NL;    // nodes per block: 4 or 16
  constexpr int EPP = 16;          // NL/HEADS: edges per register slot
  constexpr int JMAX = CAP / EPP;  // 6

  int tid = threadIdx.x;
  int ln = tid % NL;
  int node = blockIdx.x * NPB + tid / NL;  // grids exact: NN%4==0, NN%16==0
  int p0 = row_ptr[node], p1 = row_ptr[node + 1];
  int deg = p1 - p0;
  int base = (tid & 63) & ~(NL - 1);  // node's base lane within wave
  const uint32* H32 = (const uint32*)Hh;
  const float4* A4 = (const float4*)attr_csr;
  int c = 2 * ln;
  int hc = (HEADS == 4) ? (c >> 5) : 0;

  if (deg > CAP) {
    // ---- slow fallback (never taken for this input; formal correctness) ----
    float gm0 = 0.f, gm1 = 0.f, gm2 = 0.f, gm3 = 0.f, gc = 0.f;
    if (HAS_EDGE) {
      if (HEADS == 4) {
        gm0 = foldM[hc]; gm1 = foldM[4 + hc]; gm2 = foldM[8 + hc]; gm3 = foldM[12 + hc];
        gc = foldC[hc];
      } else {
        gm0 = foldM[0]; gm1 = foldM[1]; gm2 = foldM[2]; gm3 = foldM[3];
        gc = foldC[0];
      }
    }
    float adv = a_d[node * HEADS + hc];
    float al = a_s[node * HEADS + hc] + adv;
    if (HAS_EDGE) {
      float4 m4 = ((const float4*)mean_attr)[node];
      al += fmaf(m4.x, gm0, fmaf(m4.y, gm1, fmaf(m4.z, gm2, fmaf(m4.w, gm3, gc))));
    }
    al = al >= 0.f ? al : 0.2f * al;
    float m = al;
    for (int p = p0; p < p1; ++p) {
      int s = csr_src[p];
      float a = a_s[s * HEADS + hc] + adv;
      if (HAS_EDGE) {
        float4 e4 = A4[p];
        a += fmaf(e4.x, gm0, fmaf(e4.y, gm1, fmaf(e4.z, gm2, fmaf(e4.w, gm3, gc))));
      }
      a = a >= 0.f ? a : 0.2f * a;
      m = fmaxf(m, a);
    }
    float e0 = __expf(al - m);
    float den = e0;
    uint32 u0 = H32[(size_t)node * NL + ln];
    float acc0 = e0 * bf_lo(u0), acc1 = e0 * bf_hi(u0);
    for (int p = p0; p < p1; ++p) {
      int s = csr_src[p];
      float a = a_s[s * HEADS + hc] + adv;
      if (HAS_EDGE) {
        float4 e4 = A4[p];
        a += fmaf(e4.x, gm0, fmaf(e4.y, gm1, fmaf(e4.z, gm2, fmaf(e4.w, gm3, gc))));
      }
      a = a >= 0.f ? a : 0.2f * a;
      float ex = __expf(a - m);
      den += ex;
      uint32 u = H32[(size_t)s * NL + ln];
      acc0 = fmaf(ex, bf_lo(u), acc0);
      acc1 = fmaf(ex, bf_hi(u), acc1);
    }
    float inv = 1.f / (den + 1e-16f);
    float o0 = acc0 * inv + bias[c];
    float o1 = acc1 * inv + bias[c + 1];
    if (RELU) { o0 = fmaxf(o0, 0.f); o1 = fmaxf(o1, 0.f); }
    *(float2*)&out[(size_t)node * COLS + c] = make_float2(o0, o1);
    return;
  }

  int p_rel = ln / HEADS;  // 0..15
  int h = ln % HEADS;
  float adv = a_d[node * HEADS + h];
  float fm0 = 0.f, fm1 = 0.f, fm2 = 0.f, fm3 = 0.f, fc = 0.f;
  if (HAS_EDGE) {
    if (HEADS == 4) {
      fm0 = foldM[h]; fm1 = foldM[4 + h]; fm2 = foldM[8 + h]; fm3 = foldM[12 + h];
      fc = foldC[h];
    } else {
      fm0 = foldM[0]; fm1 = foldM[1]; fm2 = foldM[2]; fm3 = foldM[3];
      fc = foldC[0];
    }
  }

  // ---- Phase A: alphas (once per edge-head), running max
  float av[JMAX];
  int sv[JMAX];
  float mpart = -1e30f;
#pragma unroll
  for (int j = 0; j < JMAX; ++j) {
    int pr = p_rel + j * EPP;
    av[j] = -1e30f;
    sv[j] = 0;
    if (pr < deg) {
      int p = p0 + pr;
      int s = csr_src[p];
      sv[j] = s;
      float a = a_s[s * HEADS + h] + adv;
      if (HAS_EDGE) {
        float4 e4 = A4[p];
        a += fmaf(e4.x, fm0, fmaf(e4.y, fm1, fmaf(e4.z, fm2, fmaf(e4.w, fm3, fc))));
      }
      a = a >= 0.f ? a : 0.2f * a;
      av[j] = a;
      mpart = fmaxf(mpart, a);
    }
  }
  float al = -1e30f;
  if (p_rel == 0) {
    al = a_s[node * HEADS + h] + adv;
    if (HAS_EDGE && deg > 0) {
      float4 m4 = ((const float4*)mean_attr)[node];
      al += fmaf(m4.x, fm0, fmaf(m4.y, fm1, fmaf(m4.z, fm2, fmaf(m4.w, fm3, fc))));
    }
    al = al >= 0.f ? al : 0.2f * al;
    mpart = fmaxf(mpart, al);
  }
  float mfull = mpart;
#pragma unroll
  for (int m = HEADS; m < NL; m <<= 1) mfull = fmaxf(mfull, __shfl_xor(mfull, m));

  // ---- Phase B: branchless exp + denominator (invalid lanes give exp->0)
  float dpart = 0.f;
#pragma unroll
  for (int j = 0; j < JMAX; ++j) {
    av[j] = __expf(av[j] - mfull);
    dpart += av[j];
  }
  float exl = 0.f;
  if (p_rel == 0) {
    exl = __expf(al - mfull);
    dpart += exl;
  }
  float den = dpart;
#pragma unroll
  for (int m = HEADS; m < NL; m <<= 1) den += __shfl_xor(den, m);

  // ---- Phase C: weighted bf16 gather; shfl-extract, then loads, then fmas
  float exl_c = __shfl(exl, base + hc);
  float den_c = __shfl(den, base + hc);
  uint32 u0 = H32[(size_t)node * NL + ln];
  float acc0 = exl_c * bf_lo(u0);
  float acc1 = exl_c * bf_hi(u0);
#pragma unroll
  for (int j = 0; j < JMAX; ++j) {
    if (j * EPP < deg) {
      float exv[EPP];
      int sval[EPP];
#pragma unroll
      for (int pp = 0; pp < EPP; ++pp) {
        int srcl = base + pp * HEADS + hc;
        exv[pp] = __shfl(av[j], srcl);
        sval[pp] = __shfl(sv[j], srcl);
      }
      uint32 uv[EPP];
#pragma unroll
      for (int pp = 0; pp < EPP; ++pp) uv[pp] = H32[(size_t)sval[pp] * NL + ln];
#pragma unroll
      for (int pp = 0; pp < EPP; ++pp) {
        acc0 = fmaf(exv[pp], bf_lo(uv[pp]), acc0);
        acc1 = fmaf(exv[pp], bf_hi(uv[pp]), acc1);
      }
    }
  }
  float inv = 1.f / (den_c + 1e-16f);
  float o0 = acc0 * inv + bias[c];
  float o1 = acc1 * inv + bias[c + 1];
  if (RELU) { o0 = fmaxf(o0, 0.f); o1 = fmaxf(o1, 0.f); }
  *(float2*)&out[(size_t)node * COLS + c] = make_float2(o0, o1);
}

// ---------------------------------------------------------------------------
// Graph boundaries (batch is sorted) + fused mean-pool/descriptor-MLP/head
// ---------------------------------------------------------------------------
__global__ void bound_kernel(const int* __restrict__ batch, int* __restrict__ bound) {
  int i = blockIdx.x * 256 + threadIdx.x;
  if (i >= NN) return;
  int bc = batch[i];
  int bp = (i == 0) ? -1 : batch[i - 1];
  for (int g = bp + 1; g <= bc; ++g) bound[g] = i;
  if (i == NN - 1)
    for (int g = bc + 1; g <= GG; ++g) bound[g] = NN;
}

__global__ void pool_final_kernel(const float* __restrict__ h4, const int* __restrict__ bound,
                                  const float* __restrict__ desc, const float* __restrict__ Wd,
                                  const float* __restrict__ bd, const float* __restrict__ Wl,
                                  const float* __restrict__ bl, float* __restrict__ outp) {
  __shared__ float part[8][32];
  int g = blockIdx.x;
  int tid = threadIdx.x;  // 256
  int r0 = bound[g], r1 = bound[g + 1];
  int cch = tid & 31, chunk = tid >> 5;
  float s = 0.f;
  for (int r = r0 + chunk; r < r1; r += 8) s += h4[r * 32 + cch];
  part[chunk][cch] = s;
  __syncthreads();
  if (tid < 64) {
    float v;
    if (tid < 32) {
      float tot = 0.f;
#pragma unroll
      for (int k = 0; k < 8; ++k) tot += part[k][tid];
      int rows = r1 - r0;
      float cnt = (float)(rows > 1 ? rows : 1);
      v = (tot / cnt) * Wl[tid];
    } else {
      int cc = tid - 32;
      float acc = bd[cc];
      for (int k = 0; k < 48; ++k) acc = fmaf(desc[g * 48 + k], Wd[k * 32 + cc], acc);
      v = fmaxf(acc, 0.f) * Wl[32 + cc];
    }
#pragma unroll
    for (int m = 32; m >= 1; m >>= 1) v += __shfl_xor(v, m);
    if (tid == 0) outp[g] = 1.f / (1.f + expf(-(v + bl[0])));
  }
}

// ---------------------------------------------------------------------------
extern "C" void kernel_launch(void* const* d_in, const int* in_sizes, int n_in,
                              void* d_out, int out_size, void* d_ws, size_t ws_size,
                              hipStream_t stream) {
  const float* x = (const float*)d_in[0];
  const int* ei = (const int*)d_in[1];
  const float* edge_attr = (const float*)d_in[2];
  const int* batch = (const int*)d_in[3];
  const float* desc = (const float*)d_in[4];
  const float* We_enc = (const float*)d_in[5];
  const float* be_enc = (const float*)d_in[6];
  const float* W1 = (const float*)d_in[7];
  const float* as1 = (const float*)d_in[8];
  const float* ad1 = (const float*)d_in[9];
  const float* b1 = (const float*)d_in[10];
  const float* W2 = (const float*)d_in[11];
  const float* We2 = (const float*)d_in[12];
  const float* as2 = (const float*)d_in[13];
  const float* ad2 = (const float*)d_in[14];
  const float* ae2 = (const float*)d_in[15];
  const float* b2 = (const float*)d_in[16];
  const float* W3 = (const float*)d_in[17];
  const float* We3 = (const float*)d_in[18];
  const float* as3 = (const float*)d_in[19];
  const float* ad3 = (const float*)d_in[20];
  const float* ae3 = (const float*)d_in[21];
  const float* b3 = (const float*)d_in[22];
  const float* W4 = (const float*)d_in[23];
  const float* We4 = (const float*)d_in[24];
  const float* as4 = (const float*)d_in[25];
  const float* ad4 = (const float*)d_in[26];
  const float* ae4 = (const float*)d_in[27];
  const float* b4 = (const float*)d_in[28];
  const float* Wd = (const float*)d_in[29];
  const float* bd = (const float*)d_in[30];
  const float* Wl = (const float*)d_in[31];
  const float* bl = (const float*)d_in[32];

  const int* srcp = ei;
  const int* dstp = ei + EE;

  char* w = (char*)d_ws;
  size_t off = 0;
  auto take = [&](size_t nbytes) -> void* {
    void* p = (void*)(w + off);
    off += (nbytes + 255) & ~(size_t)255;
    return p;
  };
  int* cnt = (int*)take(2 * NN * 4);  // [cnt | pos], zeroed in one memset
  int* pos = cnt + NN;
  int* row_ptr = (int*)take((NN + 1) * 4);
  int* csr_src = (int*)take((size_t)EE * 4);
  float* attr_csr = (float*)take((size_t)EE * 16);
  float* mean_attr = (float*)take(NN * 16);
  float* fold = (float*)take(48 * 4);
  int* partial = (int*)take(64 * 4);
  int* bound = (int*)take((GG + 1) * 4);
  float* a_s = (float*)take(NN * 16);
  float* a_d = (float*)take(NN * 16);
  __hip_bfloat16* hbuf = (__hip_bfloat16*)take((size_t)NN * 128 * 2);
  float* obuf = (float*)take((size_t)NN * 128 * 4);
  (void)ws_size;

  constexpr int NSCAN = (NN + 1023) / 1024;  // 20

  // ---- CSR build + graph bounds + fold consts
  hipMemsetAsync(cnt, 0, 2 * NN * 4, stream);
  hist_kernel<<<(EE + 255) / 256, 256, 0, stream>>>(dstp, cnt);
  scan1_kernel<<<NSCAN, 1024, 0, stream>>>(cnt, row_ptr, partial);
  scan2_kernel<<<1, 64, 0, stream>>>(partial, NSCAN);
  scan3_kernel<<<(NN + 256) / 256, 256, 0, stream>>>(row_ptr, partial);
  fold_kernel<<<1, 128, 0, stream>>>(We_enc, be_enc, We2, ae2, We3, ae3, We4, ae4, fold);
  scatter_kernel<<<(EE + 255) / 256, 256, 0, stream>>>(srcp, dstp, edge_attr, row_ptr, pos,
                                                       csr_src, attr_csr);
  attrmean_kernel<<<(NN * 4 + 255) / 256, 256, 0, stream>>>(row_ptr, attr_csr, mean_attr);
  bound_kernel<<<(NN + 255) / 256, 256, 0, stream>>>(batch, bound);

  // ---- layer 1 (8 -> 4x32, no edge feats)
  gemm1_kernel<<<NN / 8, 128, 0, stream>>>(x, W1, as1, ad1, hbuf, a_s, a_d);
  gat_agg4_kernel<4, true, false><<<NN / 4, 256, 0, stream>>>(
      hbuf, a_s, a_d, nullptr, nullptr, nullptr, nullptr, row_ptr, csr_src, b1, obuf);
  // ---- layer 2
  gemm2_kernel<128, 4><<<NN / 32, 256, 0, stream>>>(obuf, W2, as2, ad2, hbuf, a_s, a_d);
  gat_agg4_kernel<4, true, true><<<NN / 4, 256, 0, stream>>>(
      hbuf, a_s, a_d, attr_csr, mean_attr, fold + 0, fold + 16, row_ptr, csr_src, b2, obuf);
  // ---- layer 3
  gemm2_kernel<128, 4><<<NN / 32, 256, 0, stream>>>(obuf, W3, as3, ad3, hbuf, a_s, a_d);
  gat_agg4_kernel<4, true, true><<<NN / 4, 256, 0, stream>>>(
      hbuf, a_s, a_d, attr_csr, mean_attr, fold + 20, fold + 36, row_ptr, csr_src, b3, obuf);
  // ---- layer 4 (128 -> 32, heads=1, no relu)
  gemm2_kernel<32, 2><<<(NN + 63) / 64, 256, 0, stream>>>(obuf, W4, as4, ad4, hbuf, a_s, a_d);
  gat_agg4_kernel<1, false, true><<<NN / 16, 256, 0, stream>>>(
      hbuf, a_s, a_d, attr_csr, mean_attr, fold + 40, fold + 44, row_ptr, csr_src, b4, obuf);

  // ---- fused pool + descriptor MLP + final linear + sigmoid
  pool_final_kernel<<<GG, 256, 0, stream>>>(obuf, bound, desc, Wd, bd, Wl, bl, (float*)d_out);
}

// Round 8
// 341.590 us; speedup vs baseline: 2.4174x; 1.0358x over previous
//
#include <hip/hip_runtime.h>
#include <hip/hip_bf16.h>
#include <math.h>

#define NN 20000
#define EE 480000
#define GG 200
#define CAP 96  // fast-path max degree (true max deg ~55); fallback is correct anyway

typedef unsigned int uint32;

static __device__ inline unsigned short f2bf(float f) {
  __hip_bfloat16 h = __float2bfloat16(f);
  return *reinterpret_cast<const unsigned short*>(&h);
}
static __device__ inline float bf2f(unsigned short u) {
  return __uint_as_float(((uint32)u) << 16);
}
static __device__ inline float bf_lo(uint32 u) { return __uint_as_float(u << 16); }
static __device__ inline float bf_hi(uint32 u) { return __uint_as_float(u & 0xffff0000u); }
static __device__ inline uint32 pack2(float lo, float hi) {
  return ((uint32)f2bf(lo)) | (((uint32)f2bf(hi)) << 16);
}

// ---------------------------------------------------------------------------
// CSR build: histogram by dst, multi-block scan, scatter (src + bf16 attr)
// ---------------------------------------------------------------------------
__global__ void hist_kernel(const int* __restrict__ dst, int* __restrict__ cnt) {
  int i = blockIdx.x * 256 + threadIdx.x;
  if (i < EE) atomicAdd(&cnt[dst[i]], 1);
}

__global__ void scan1_kernel(const int* __restrict__ cnt, int* __restrict__ row_ptr,
                             int* __restrict__ partial) {
  __shared__ int buf[1024];
  int t = threadIdx.x;
  int i = blockIdx.x * 1024 + t;
  int v = (i < NN) ? cnt[i] : 0;
  buf[t] = v;
  __syncthreads();
  for (int offd = 1; offd < 1024; offd <<= 1) {
    int tmp = (t >= offd) ? buf[t - offd] : 0;
    __syncthreads();
    buf[t] += tmp;
    __syncthreads();
  }
  if (i < NN) row_ptr[i + 1] = buf[t];  // inclusive within block
  if (t == 1023) partial[blockIdx.x] = buf[1023];
}

__global__ void scan2_kernel(int* __restrict__ partial, int nblk) {
  int t = threadIdx.x;  // 64 threads, one wave
  int v = (t < nblk) ? partial[t] : 0;
  for (int offd = 1; offd < 32; offd <<= 1) {
    int u = __shfl_up(v, offd);
    if (t >= offd) v += u;
  }
  if (t < nblk) partial[t] = v;  // inclusive
}

__global__ void scan3_kernel(int* __restrict__ row_ptr, const int* __restrict__ partial) {
  int i = blockIdx.x * 256 + threadIdx.x;
  if (i == 0) row_ptr[0] = 0;
  if (i >= 1 && i <= NN) {
    int b = (i - 1) >> 10;
    if (b > 0) row_ptr[i] += partial[b - 1];
  }
}

__global__ void scatter_kernel(const int* __restrict__ src, const int* __restrict__ dst,
                               const float* __restrict__ attr, const int* __restrict__ row_ptr,
                               int* __restrict__ pos, int* __restrict__ csr_src,
                               uint2* __restrict__ attr_pk) {
  int e = blockIdx.x * 256 + threadIdx.x;
  if (e >= EE) return;
  int d = dst[e];
  int p = row_ptr[d] + atomicAdd(&pos[d], 1);
  csr_src[p] = src[e];
  float4 a = ((const float4*)attr)[e];
  uint2 q;
  q.x = pack2(a.x, a.y);
  q.y = pack2(a.z, a.w);
  attr_pk[p] = q;
}

// ---------------------------------------------------------------------------
// aux kernel: [0,79) per-node mean of bf16 attrs; [79,158) graph bounds;
// block 158: fold constants (edge-attention 4x4 matvec per layer).
// fold layout (floats): [0..15]=M2(i*4+h) [16..19]=c2 [20..35]=M3 [36..39]=c3
//                       [40..43]=M4 [44]=c4
// ---------------------------------------------------------------------------
#define AMB ((NN + 255) / 256)  // 79

__global__ void aux_kernel(const int* __restrict__ row_ptr, const uint2* __restrict__ attr_pk,
                           float* __restrict__ mean_attr, const int* __restrict__ batch,
                           int* __restrict__ bound, const float* __restrict__ We_enc,
                           const float* __restrict__ be_enc, const float* __restrict__ We2,
                           const float* __restrict__ ae2, const float* __restrict__ We3,
                           const float* __restrict__ ae3, const float* __restrict__ We4,
                           const float* __restrict__ ae4, float* __restrict__ fold) {
  int b = blockIdx.x;
  int t = threadIdx.x;
  if (b < AMB) {
    // ---- per-node attr mean
    int node = b * 256 + t;
    if (node < NN) {
      int p0 = row_ptr[node], p1 = row_ptr[node + 1];
      float s0 = 0.f, s1 = 0.f, s2 = 0.f, s3 = 0.f;
      for (int p = p0; p < p1; ++p) {
        uint2 q = attr_pk[p];
        s0 += bf_lo(q.x); s1 += bf_hi(q.x);
        s2 += bf_lo(q.y); s3 += bf_hi(q.y);
      }
      int deg = p1 - p0;
      float inv = 1.f / (float)(deg > 1 ? deg : 1);
      ((float4*)mean_attr)[node] = make_float4(s0 * inv, s1 * inv, s2 * inv, s3 * inv);
    }
    return;
  }
  if (b < 2 * AMB) {
    // ---- graph boundaries (batch sorted)
    int i = (b - AMB) * 256 + t;
    if (i >= NN) return;
    int bc = batch[i];
    int bp = (i == 0) ? -1 : batch[i - 1];
    for (int g = bp + 1; g <= bc; ++g) bound[g] = i;
    if (i == NN - 1)
      for (int g = bc + 1; g <= GG; ++g) bound[g] = NN;
    return;
  }
  // ---- fold constants (256 threads; compute guarded to t<128, barriers not)
  __shared__ float V[32 * 4];
  if (t < 128) {
    int k = t >> 2, h = t & 3;
    float s = 0.f;
    for (int c = 0; c < 32; ++c) s = fmaf(We2[k * 128 + h * 32 + c], ae2[h * 32 + c], s);
    V[k * 4 + h] = s;
  }
  __syncthreads();
  if (t < 16) {
    int i = t >> 2, h = t & 3;
    float s = 0.f;
    for (int k = 0; k < 32; ++k) s = fmaf(We_enc[i * 32 + k], V[k * 4 + h], s);
    fold[i * 4 + h] = s;
  } else if (t < 20) {
    int h = t - 16;
    float s = 0.f;
    for (int k = 0; k < 32; ++k) s = fmaf(be_enc[k], V[k * 4 + h], s);
    fold[16 + h] = s;
  }
  __syncthreads();
  if (t < 128) {
    int k = t >> 2, h = t & 3;
    float s = 0.f;
    for (int c = 0; c < 32; ++c) s = fmaf(We3[k * 128 + h * 32 + c], ae3[h * 32 + c], s);
    V[k * 4 + h] = s;
  }
  __syncthreads();
  if (t < 16) {
    int i = t >> 2, h = t & 3;
    float s = 0.f;
    for (int k = 0; k < 32; ++k) s = fmaf(We_enc[i * 32 + k], V[k * 4 + h], s);
    fold[20 + i * 4 + h] = s;
  } else if (t < 20) {
    int h = t - 16;
    float s = 0.f;
    for (int k = 0; k < 32; ++k) s = fmaf(be_enc[k], V[k * 4 + h], s);
    fold[36 + h] = s;
  }
  __syncthreads();
  if (t < 32) {
    float s = 0.f;
    for (int c = 0; c < 32; ++c) s = fmaf(We4[t * 32 + c], ae4[c], s);
    V[t] = s;
  }
  __syncthreads();
  if (t < 4) {
    float s = 0.f;
    for (int k = 0; k < 32; ++k) s = fmaf(We_enc[t * 32 + k], V[k], s);
    fold[40 + t] = s;
  } else if (t == 4) {
    float s = 0.f;
    for (int k = 0; k < 32; ++k) s = fmaf(be_enc[k], V[k], s);
    fold[44] = s;
  }
}

// ---------------------------------------------------------------------------
// Node GEMM v1 (layer 1, K=8): H = X @ W, bf16 H, fused a_s/a_d reductions.
// ---------------------------------------------------------------------------
__global__ void gemm1_kernel(const float* __restrict__ X, const float* __restrict__ W,
                             const float* __restrict__ att_s, const float* __restrict__ att_d,
                             __hip_bfloat16* __restrict__ H, float* __restrict__ a_s,
                             float* __restrict__ a_d) {
  constexpr int K = 8;
  constexpr int COLS = 128;
  constexpr int ROWS = 8;
  __shared__ float xs[ROWS][K];
  int tid = threadIdx.x;
  int row0 = blockIdx.x * ROWS;
  if (tid < ROWS * K) xs[tid / K][tid % K] = X[row0 * K + tid];
  __syncthreads();
  int c = tid;  // 128 threads = 128 cols
  float acc[ROWS];
#pragma unroll
  for (int j = 0; j < ROWS; ++j) acc[j] = 0.f;
  for (int k = 0; k < K; ++k) {
    float wv = W[k * COLS + c];
#pragma unroll
    for (int j = 0; j < ROWS; ++j) acc[j] = fmaf(xs[j][k], wv, acc[j]);
  }
  float asv = att_s[c], adv = att_d[c];
#pragma unroll
  for (int j = 0; j < ROWS; ++j) {
    int row = row0 + j;
    float vs = acc[j] * asv, vd = acc[j] * adv;
#pragma unroll
    for (int m = 16; m >= 1; m >>= 1) {
      vs += __shfl_xor(vs, m);
      vd += __shfl_xor(vd, m);
    }
    H[row * COLS + c] = __float2bfloat16(acc[j]);
    if ((tid & 31) == 0) {
      a_s[row * 4 + (c >> 5)] = vs;
      a_d[row * 4 + (c >> 5)] = vd;
    }
  }
}

// ---------------------------------------------------------------------------
// Node GEMM v2 (K=128): register-tiled TRx4, W staged in LDS as bf16,
// X tile fp32 in LDS. Fused a_s/a_d head reductions.
// ---------------------------------------------------------------------------
template <int COLS, int TR>
__global__ __launch_bounds__(256) void gemm2_kernel(const float* __restrict__ X,
                                                    const float* __restrict__ W,
                                                    const float* __restrict__ att_s,
                                                    const float* __restrict__ att_d,
                                                    __hip_bfloat16* __restrict__ H,
                                                    float* __restrict__ a_s,
                                                    float* __restrict__ a_d) {
  constexpr int K = 128;
  constexpr int HEADS = COLS / 32;
  constexpr int CG = COLS / 4;   // col-groups (4 cols each)
  constexpr int RG = 256 / CG;   // row-groups
  constexpr int ROWS = RG * TR;  // rows per block
  __shared__ unsigned short ws[K * COLS];  // bf16 bits, [k][c]
  __shared__ float xs[ROWS * K];           // [r][k]
  int tid = threadIdx.x;
  int row0 = blockIdx.x * ROWS;
  // stage W -> bf16 LDS
  for (int i = tid * 4; i < K * COLS; i += 1024) {
    float4 wv = *(const float4*)&W[i];
    ushort4 u;
    u.x = f2bf(wv.x); u.y = f2bf(wv.y); u.z = f2bf(wv.z); u.w = f2bf(wv.w);
    *(ushort4*)&ws[i] = u;
  }
  // stage X tile (guarded, zero-fill)
  for (int i = tid * 4; i < ROWS * K; i += 1024) {
    int grow = row0 + i / K;
    float4 v = make_float4(0.f, 0.f, 0.f, 0.f);
    if (grow < NN) v = *(const float4*)&X[(size_t)grow * K + (i & (K - 1))];
    *(float4*)&xs[i] = v;
  }
  __syncthreads();
  int cg = tid % CG, rg = tid / CG;
  int c0 = cg * 4, r0 = rg * TR;
  float acc[TR][4];
#pragma unroll
  for (int i = 0; i < TR; ++i)
#pragma unroll
    for (int j = 0; j < 4; ++j) acc[i][j] = 0.f;
  for (int k0 = 0; k0 < K; k0 += 4) {
    float w4[4][4];
#pragma unroll
    for (int j = 0; j < 4; ++j) {  // j = k offset
      ushort4 u = *(ushort4*)&ws[(k0 + j) * COLS + c0];
      w4[j][0] = bf2f(u.x); w4[j][1] = bf2f(u.y); w4[j][2] = bf2f(u.z); w4[j][3] = bf2f(u.w);
    }
#pragma unroll
    for (int i = 0; i < TR; ++i) {
      float4 xv = *(float4*)&xs[(r0 + i) * K + k0];
#pragma unroll
      for (int j = 0; j < 4; ++j) {
        acc[i][j] = fmaf(xv.x, w4[0][j], acc[i][j]);
        acc[i][j] = fmaf(xv.y, w4[1][j], acc[i][j]);
        acc[i][j] = fmaf(xv.z, w4[2][j], acc[i][j]);
        acc[i][j] = fmaf(xv.w, w4[3][j], acc[i][j]);
      }
    }
  }
  float as4[4], ad4[4];
#pragma unroll
  for (int j = 0; j < 4; ++j) { as4[j] = att_s[c0 + j]; ad4[j] = att_d[c0 + j]; }
  int h = c0 >> 5;
#pragma unroll
  for (int i = 0; i < TR; ++i) {
    int row = row0 + r0 + i;
    ushort4 hv;
    hv.x = f2bf(acc[i][0]); hv.y = f2bf(acc[i][1]); hv.z = f2bf(acc[i][2]); hv.w = f2bf(acc[i][3]);
    if (row < NN) *(ushort4*)&H[(size_t)row * COLS + c0] = hv;
    float vs = 0.f, vd = 0.f;
#pragma unroll
    for (int j = 0; j < 4; ++j) {
      vs = fmaf(acc[i][j], as4[j], vs);
      vd = fmaf(acc[i][j], ad4[j], vd);
    }
#pragma unroll
    for (int m = 1; m <= 4; m <<= 1) {
      vs += __shfl_xor(vs, m);
      vd += __shfl_xor(vd, m);
    }
    if ((tid & 7) == 0 && row < NN) {
      a_s[row * HEADS + h] = vs;
      a_d[row * HEADS + h] = vd;
    }
  }
}

// ---------------------------------------------------------------------------
// GAT aggregation v4: all-shuffle, zero LDS, branchless softmax, edge alphas
// computed on the fly from packed bf16 attrs via the fold matvec.
// ---------------------------------------------------------------------------
template <int HEADS, bool RELU, bool HAS_EDGE>
__global__ __launch_bounds__(256) void gat_agg4_kernel(
    const __hip_bfloat16* __restrict__ Hh, const float* __restrict__ a_s,
    const float* __restrict__ a_d, const uint2* __restrict__ attr_pk,
    const float* __restrict__ mean_attr, const float* __restrict__ foldM,
    const float* __restrict__ foldC, const int* __restrict__ row_ptr,
    const int* __restrict__ csr_src, const float* __restrict__ bias,
    float* __restrict__ out) {
  constexpr int COLS = HEADS * 32;
  constexpr int NL = COLS / 2;     // lanes per node: 64 (H=4) or 16 (H=1)
  constexpr int NPB = 256 / NL;    // nodes per block: 4 or 16
  constexpr int EPP = 16;          // NL/HEADS: edges per register slot
  constexpr int JMAX = CAP / EPP;  // 6

  int tid = threadIdx.x;
  int ln = tid % NL;
  int node = blockIdx.x * NPB + tid / NL;  // grids exact: NN%4==0, NN%16==0
  int p0 = row_ptr[node], p1 = row_ptr[node + 1];
  int deg = p1 - p0;
  int base = (tid & 63) & ~(NL - 1);  // node's base lane within wave
  const uint32* H32 = (const uint32*)Hh;
  int c = 2 * ln;
  int hc = (HEADS == 4) ? (c >> 5) : 0;

  if (deg > CAP) {
    // ---- slow fallback (never taken for this input; formal correctness) ----
    float gm0 = 0.f, gm1 = 0.f, gm2 = 0.f, gm3 = 0.f, gc = 0.f;
    if (HAS_EDGE) {
      if (HEADS == 4) {
        gm0 = foldM[hc]; gm1 = foldM[4 + hc]; gm2 = foldM[8 + hc]; gm3 = foldM[12 + hc];
        gc = foldC[hc];
      } else {
        gm0 = foldM[0]; gm1 = foldM[1]; gm2 = foldM[2]; gm3 = foldM[3];
        gc = foldC[0];
      }
    }
    float adv = a_d[node * HEADS + hc];
    float al = a_s[node * HEADS + hc] + adv;
    if (HAS_EDGE) {
      float4 m4 = ((const float4*)mean_attr)[node];
      al += fmaf(m4.x, gm0, fmaf(m4.y, gm1, fmaf(m4.z, gm2, fmaf(m4.w, gm3, gc))));
    }
    al = al >= 0.f ? al : 0.2f * al;
    float m = al;
    for (int p = p0; p < p1; ++p) {
      int s = csr_src[p];
      float a = a_s[s * HEADS + hc] + adv;
      if (HAS_EDGE) {
        uint2 q = attr_pk[p];
        a += fmaf(bf_lo(q.x), gm0,
                  fmaf(bf_hi(q.x), gm1, fmaf(bf_lo(q.y), gm2, fmaf(bf_hi(q.y), gm3, gc))));
      }
      a = a >= 0.f ? a : 0.2f * a;
      m = fmaxf(m, a);
    }
    float e0 = __expf(al - m);
    float den = e0;
    uint32 u0 = H32[(size_t)node * NL + ln];
    float acc0 = e0 * bf_lo(u0), acc1 = e0 * bf_hi(u0);
    for (int p = p0; p < p1; ++p) {
      int s = csr_src[p];
      float a = a_s[s * HEADS + hc] + adv;
      if (HAS_EDGE) {
        uint2 q = attr_pk[p];
        a += fmaf(bf_lo(q.x), gm0,
                  fmaf(bf_hi(q.x), gm1, fmaf(bf_lo(q.y), gm2, fmaf(bf_hi(q.y), gm3, gc))));
      }
      a = a >= 0.f ? a : 0.2f * a;
      float ex = __expf(a - m);
      den += ex;
      uint32 u = H32[(size_t)s * NL + ln];
      acc0 = fmaf(ex, bf_lo(u), acc0);
      acc1 = fmaf(ex, bf_hi(u), acc1);
    }
    float inv = 1.f / (den + 1e-16f);
    float o0 = acc0 * inv + bias[c];
    float o1 = acc1 * inv + bias[c + 1];
    if (RELU) { o0 = fmaxf(o0, 0.f); o1 = fmaxf(o1, 0.f); }
    *(float2*)&out[(size_t)node * COLS + c] = make_float2(o0, o1);
    return;
  }

  int p_rel = ln / HEADS;  // 0..15
  int h = ln % HEADS;
  float adv = a_d[node * HEADS + h];
  float fm0 = 0.f, fm1 = 0.f, fm2 = 0.f, fm3 = 0.f, fc = 0.f;
  if (HAS_EDGE) {
    if (HEADS == 4) {
      fm0 = foldM[h]; fm1 = foldM[4 + h]; fm2 = foldM[8 + h]; fm3 = foldM[12 + h];
      fc = foldC[h];
    } else {
      fm0 = foldM[0]; fm1 = foldM[1]; fm2 = foldM[2]; fm3 = foldM[3];
      fc = foldC[0];
    }
  }

  // ---- Phase A: alphas (once per edge-head), running max
  float av[JMAX];
  int sv[JMAX];
  float mpart = -1e30f;
#pragma unroll
  for (int j = 0; j < JMAX; ++j) {
    int pr = p_rel + j * EPP;
    av[j] = -1e30f;
    sv[j] = 0;
    if (pr < deg) {
      int p = p0 + pr;
      int s = csr_src[p];
      sv[j] = s;
      float a = a_s[s * HEADS + h] + adv;
      if (HAS_EDGE) {
        uint2 q = attr_pk[p];
        a += fmaf(bf_lo(q.x), fm0,
                  fmaf(bf_hi(q.x), fm1, fmaf(bf_lo(q.y), fm2, fmaf(bf_hi(q.y), fm3, fc))));
      }
      a = a >= 0.f ? a : 0.2f * a;
      av[j] = a;
      mpart = fmaxf(mpart, a);
    }
  }
  float al = -1e30f;
  if (p_rel == 0) {
    al = a_s[node * HEADS + h] + adv;
    if (HAS_EDGE && deg > 0) {
      float4 m4 = ((const float4*)mean_attr)[node];
      al += fmaf(m4.x, fm0, fmaf(m4.y, fm1, fmaf(m4.z, fm2, fmaf(m4.w, fm3, fc))));
    }
    al = al >= 0.f ? al : 0.2f * al;
    mpart = fmaxf(mpart, al);
  }
  float mfull = mpart;
#pragma unroll
  for (int m = HEADS; m < NL; m <<= 1) mfull = fmaxf(mfull, __shfl_xor(mfull, m));

  // ---- Phase B: branchless exp + denominator (invalid lanes give exp->0)
  float dpart = 0.f;
#pragma unroll
  for (int j = 0; j < JMAX; ++j) {
    av[j] = __expf(av[j] - mfull);
    dpart += av[j];
  }
  float exl = 0.f;
  if (p_rel == 0) {
    exl = __expf(al - mfull);
    dpart += exl;
  }
  float den = dpart;
#pragma unroll
  for (int m = HEADS; m < NL; m <<= 1) den += __shfl_xor(den, m);

  // ---- Phase C: weighted bf16 gather; shfl-extract, then loads, then fmas
  float exl_c = __shfl(exl, base + hc);
  float den_c = __shfl(den, base + hc);
  uint32 u0 = H32[(size_t)node * NL + ln];
  float acc0 = exl_c * bf_lo(u0);
  float acc1 = exl_c * bf_hi(u0);
#pragma unroll
  for (int j = 0; j < JMAX; ++j) {
    if (j * EPP < deg) {
      float exv[EPP];
      int sval[EPP];
#pragma unroll
      for (int pp = 0; pp < EPP; ++pp) {
        int srcl = base + pp * HEADS + hc;
        exv[pp] = __shfl(av[j], srcl);
        sval[pp] = __shfl(sv[j], srcl);
      }
      uint32 uv[EPP];
#pragma unroll
      for (int pp = 0; pp < EPP; ++pp) uv[pp] = H32[(size_t)sval[pp] * NL + ln];
#pragma unroll
      for (int pp = 0; pp < EPP; ++pp) {
        acc0 = fmaf(exv[pp], bf_lo(uv[pp]), acc0);
        acc1 = fmaf(exv[pp], bf_hi(uv[pp]), acc1);
      }
    }
  }
  float inv = 1.f / (den_c + 1e-16f);
  float o0 = acc0 * inv + bias[c];
  float o1 = acc1 * inv + bias[c + 1];
  if (RELU) { o0 = fmaxf(o0, 0.f); o1 = fmaxf(o1, 0.f); }
  *(float2*)&out[(size_t)node * COLS + c] = make_float2(o0, o1);
}

// ---------------------------------------------------------------------------
// Fused mean-pool + descriptor MLP + final linear + sigmoid
// ---------------------------------------------------------------------------
__global__ void pool_final_kernel(const float* __restrict__ h4, const int* __restrict__ bound,
                                  const float* __restrict__ desc, const float* __restrict__ Wd,
                                  const float* __restrict__ bd, const float* __restrict__ Wl,
                                  const float* __restrict__ bl, float* __restrict__ outp) {
  __shared__ float part[8][32];
  int g = blockIdx.x;
  int tid = threadIdx.x;  // 256
  int r0 = bound[g], r1 = bound[g + 1];
  int cch = tid & 31, chunk = tid >> 5;
  float s = 0.f;
  for (int r = r0 + chunk; r < r1; r += 8) s += h4[r * 32 + cch];
  part[chunk][cch] = s;
  __syncthreads();
  if (tid < 64) {
    float v;
    if (tid < 32) {
      float tot = 0.f;
#pragma unroll
      for (int k = 0; k < 8; ++k) tot += part[k][tid];
      int rows = r1 - r0;
      float cnt = (float)(rows > 1 ? rows : 1);
      v = (tot / cnt) * Wl[tid];
    } else {
      int cc = tid - 32;
      float acc = bd[cc];
      for (int k = 0; k < 48; ++k) acc = fmaf(desc[g * 48 + k], Wd[k * 32 + cc], acc);
      v = fmaxf(acc, 0.f) * Wl[32 + cc];
    }
#pragma unroll
    for (int m = 32; m >= 1; m >>= 1) v += __shfl_xor(v, m);
    if (tid == 0) outp[g] = 1.f / (1.f + expf(-(v + bl[0])));
  }
}

// ---------------------------------------------------------------------------
extern "C" void kernel_launch(void* const* d_in, const int* in_sizes, int n_in,
                              void* d_out, int out_size, void* d_ws, size_t ws_size,
                              hipStream_t stream) {
  const float* x = (const float*)d_in[0];
  const int* ei = (const int*)d_in[1];
  const float* edge_attr = (const float*)d_in[2];
  const int* batch = (const int*)d_in[3];
  const float* desc = (const float*)d_in[4];
  const float* We_enc = (const float*)d_in[5];
  const float* be_enc = (const float*)d_in[6];
  const float* W1 = (const float*)d_in[7];
  const float* as1 = (const float*)d_in[8];
  const float* ad1 = (const float*)d_in[9];
  const float* b1 = (const float*)d_in[10];
  const float* W2 = (const float*)d_in[11];
  const float* We2 = (const float*)d_in[12];
  const float* as2 = (const float*)d_in[13];
  const float* ad2 = (const float*)d_in[14];
  const float* ae2 = (const float*)d_in[15];
  const float* b2 = (const float*)d_in[16];
  const float* W3 = (const float*)d_in[17];
  const float* We3 = (const float*)d_in[18];
  const float* as3 = (const float*)d_in[19];
  const float* ad3 = (const float*)d_in[20];
  const float* ae3 = (const float*)d_in[21];
  const float* b3 = (const float*)d_in[22];
  const float* W4 = (const float*)d_in[23];
  const float* We4 = (const float*)d_in[24];
  const float* as4 = (const float*)d_in[25];
  const float* ad4 = (const float*)d_in[26];
  const float* ae4 = (const float*)d_in[27];
  const float* b4 = (const float*)d_in[28];
  const float* Wd = (const float*)d_in[29];
  const float* bd = (const float*)d_in[30];
  const float* Wl = (const float*)d_in[31];
  const float* bl = (const float*)d_in[32];

  const int* srcp = ei;
  const int* dstp = ei + EE;

  char* w = (char*)d_ws;
  size_t off = 0;
  auto take = [&](size_t nbytes) -> void* {
    void* p = (void*)(w + off);
    off += (nbytes + 255) & ~(size_t)255;
    return p;
  };
  int* cnt = (int*)take(2 * NN * 4);  // [cnt | pos], zeroed in one memset
  int* pos = cnt + NN;
  int* row_ptr = (int*)take((NN + 1) * 4);
  int* csr_src = (int*)take((size_t)EE * 4);
  uint2* attr_pk = (uint2*)take((size_t)EE * 8);
  float* mean_attr = (float*)take(NN * 16);
  float* fold = (float*)take(48 * 4);
  int* partial = (int*)take(64 * 4);
  int* bound = (int*)take((GG + 1) * 4);
  float* a_s = (float*)take(NN * 16);
  float* a_d = (float*)take(NN * 16);
  __hip_bfloat16* hbuf = (__hip_bfloat16*)take((size_t)NN * 128 * 2);
  float* obuf = (float*)take((size_t)NN * 128 * 4);
  (void)ws_size;

  constexpr int NSCAN = (NN + 1023) / 1024;  // 20

  // ---- CSR build + aux (attr means, graph bounds, fold consts)
  hipMemsetAsync(cnt, 0, 2 * NN * 4, stream);
  hist_kernel<<<(EE + 255) / 256, 256, 0, stream>>>(dstp, cnt);
  scan1_kernel<<<NSCAN, 1024, 0, stream>>>(cnt, row_ptr, partial);
  scan2_kernel<<<1, 64, 0, stream>>>(partial, NSCAN);
  scan3_kernel<<<(NN + 256) / 256, 256, 0, stream>>>(row_ptr, partial);
  scatter_kernel<<<(EE + 255) / 256, 256, 0, stream>>>(srcp, dstp, edge_attr, row_ptr, pos,
                                                       csr_src, attr_pk);
  aux_kernel<<<2 * AMB + 1, 256, 0, stream>>>(row_ptr, attr_pk, mean_attr, batch, bound, We_enc,
                                              be_enc, We2, ae2, We3, ae3, We4, ae4, fold);

  // ---- layer 1 (8 -> 4x32, no edge feats)
  gemm1_kernel<<<NN / 8, 128, 0, stream>>>(x, W1, as1, ad1, hbuf, a_s, a_d);
  gat_agg4_kernel<4, true, false><<<NN / 4, 256, 0, stream>>>(
      hbuf, a_s, a_d, nullptr, nullptr, nullptr, nullptr, row_ptr, csr_src, b1, obuf);
  // ---- layer 2
  gemm2_kernel<128, 4><<<NN / 32, 256, 0, stream>>>(obuf, W2, as2, ad2, hbuf, a_s, a_d);
  gat_agg4_kernel<4, true, true><<<NN / 4, 256, 0, stream>>>(
      hbuf, a_s, a_d, attr_pk, mean_attr, fold + 0, fold + 16, row_ptr, csr_src, b2, obuf);
  // ---- layer 3
  gemm2_kernel<128, 4><<<NN / 32, 256, 0, stream>>>(obuf, W3, as3, ad3, hbuf, a_s, a_d);
  gat_agg4_kernel<4, true, true><<<NN / 4, 256, 0, stream>>>(
      hbuf, a_s, a_d, attr_pk, mean_attr, fold + 20, fold + 36, row_ptr, csr_src, b3, obuf);
  // ---- layer 4 (128 -> 32, heads=1, no relu)
  gemm2_kernel<32, 2><<<(NN + 63) / 64, 256, 0, stream>>>(obuf, W4, as4, ad4, hbuf, a_s, a_d);
  gat_agg4_kernel<1, false, true><<<NN / 16, 256, 0, stream>>>(
      hbuf, a_s, a_d, attr_pk, mean_attr, fold + 40, fold + 44, row_ptr, csr_src, b4, obuf);

  // ---- fused pool + descriptor MLP + final linear + sigmoid
  pool_final_kernel<<<GG, 256, 0, stream>>>(obuf, bound, desc, Wd, bd, Wl, bl, (float*)d_out);
}

// Round 13
// 331.752 us; speedup vs baseline: 2.4891x; 1.0297x over previous
//
#include <hip/hip_runtime.h>
#include <hip/hip_bf16.h>
#include <math.h>

#define NN 20000
#define EE 480000
#define GG 200
#define CAP 96  // fast-path max degree (true max deg ~55); fallback is correct anyway

typedef unsigned int uint32;

static __device__ inline unsigned short f2bf(float f) {
  __hip_bfloat16 h = __float2bfloat16(f);
  return *reinterpret_cast<const unsigned short*>(&h);
}
static __device__ inline float bf2f(unsigned short u) {
  return __uint_as_float(((uint32)u) << 16);
}
static __device__ inline float bf_lo(uint32 u) { return __uint_as_float(u << 16); }
static __device__ inline float bf_hi(uint32 u) { return __uint_as_float(u & 0xffff0000u); }
static __device__ inline uint32 pack2(float lo, float hi) {
  return ((uint32)f2bf(lo)) | (((uint32)f2bf(hi)) << 16);
}

// ---------------------------------------------------------------------------
// Fused hist + gemm1: blocks [0,HB) histogram dst; blocks [HB,HB+GB) do
// layer-1 GEMM (K=8 -> 128 cols, 16 rows/block), bf16 H, fused a_s/a_d.
// ---------------------------------------------------------------------------
#define HB ((EE + 255) / 256)  // 1875
#define GB (NN / 16)           // 1250

__global__ void histgemm1_kernel(const int* __restrict__ dst, int* __restrict__ cnt,
                                 const float* __restrict__ X, const float* __restrict__ W,
                                 const float* __restrict__ att_s, const float* __restrict__ att_d,
                                 __hip_bfloat16* __restrict__ H, float* __restrict__ a_s,
                                 float* __restrict__ a_d) {
  int tid = threadIdx.x;
  if (blockIdx.x < HB) {
    int i = blockIdx.x * 256 + tid;
    if (i < EE) atomicAdd(&cnt[dst[i]], 1);
    return;
  }
  __shared__ float xs[16][8];
  int row0 = (blockIdx.x - HB) * 16;
  if (tid < 128) xs[tid >> 3][tid & 7] = X[row0 * 8 + tid];
  __syncthreads();
  int c = tid & 127;
  int half = tid >> 7;  // rows [8*half, 8*half+8)
  float acc[8];
#pragma unroll
  for (int j = 0; j < 8; ++j) acc[j] = 0.f;
  for (int k = 0; k < 8; ++k) {
    float wv = W[k * 128 + c];
#pragma unroll
    for (int j = 0; j < 8; ++j) acc[j] = fmaf(xs[half * 8 + j][k], wv, acc[j]);
  }
  float asv = att_s[c], adv = att_d[c];
#pragma unroll
  for (int j = 0; j < 8; ++j) {
    int row = row0 + half * 8 + j;
    float vs = acc[j] * asv, vd = acc[j] * adv;
#pragma unroll
    for (int m = 16; m >= 1; m >>= 1) {
      vs += __shfl_xor(vs, m);
      vd += __shfl_xor(vd, m);
    }
    H[row * 128 + c] = __float2bfloat16(acc[j]);
    if ((tid & 31) == 0) {
      a_s[row * 4 + (c >> 5)] = vs;
      a_d[row * 4 + (c >> 5)] = vd;
    }
  }
}

// ---------------------------------------------------------------------------
// CSR build: multi-block scan (scan2 folded into scan3), scatter
// ---------------------------------------------------------------------------
#define NSCAN ((NN + 1023) / 1024)  // 20

__global__ void scan1_kernel(const int* __restrict__ cnt, int* __restrict__ row_ptr,
                             int* __restrict__ partial) {
  __shared__ int buf[1024];
  int t = threadIdx.x;
  int i = blockIdx.x * 1024 + t;
  int v = (i < NN) ? cnt[i] : 0;
  buf[t] = v;
  __syncthreads();
  for (int offd = 1; offd < 1024; offd <<= 1) {
    int tmp = (t >= offd) ? buf[t - offd] : 0;
    __syncthreads();
    buf[t] += tmp;
    __syncthreads();
  }
  if (i < NN) row_ptr[i + 1] = buf[t];  // inclusive within block
  if (t == 1023) partial[blockIdx.x] = buf[1023];
}

__global__ void scan23_kernel(int* __restrict__ row_ptr, const int* __restrict__ partial) {
  __shared__ int sc[NSCAN];
  int t = threadIdx.x;
  if (t < 64) {
    int v = (t < NSCAN) ? partial[t] : 0;
    for (int o = 1; o < 32; o <<= 1) {
      int u = __shfl_up(v, o);
      if (t >= o) v += u;
    }
    if (t < NSCAN) sc[t] = v;  // inclusive scan of partials
  }
  __syncthreads();
  int i = blockIdx.x * 256 + t;
  if (i == 0) row_ptr[0] = 0;
  if (i >= 1 && i <= NN) {
    int b = (i - 1) >> 10;
    if (b > 0) row_ptr[i] += sc[b - 1];
  }
}

__global__ void scatter_kernel(const int* __restrict__ src, const int* __restrict__ dst,
                               const float* __restrict__ attr, const int* __restrict__ row_ptr,
                               int* __restrict__ pos, int* __restrict__ csr_src,
                               uint2* __restrict__ attr_pk) {
  int e = blockIdx.x * 256 + threadIdx.x;
  if (e >= EE) return;
  int d = dst[e];
  int p = row_ptr[d] + atomicAdd(&pos[d], 1);
  csr_src[p] = src[e];
  float4 a = ((const float4*)attr)[e];
  uint2 q;
  q.x = pack2(a.x, a.y);
  q.y = pack2(a.z, a.w);
  attr_pk[p] = q;
}

// ---------------------------------------------------------------------------
// aux kernel: [0,79) per-node mean of bf16 attrs; [79,158) graph bounds;
// block 158: fold constants (edge-attention 4x4 matvec per layer).
// fold layout (floats): [0..15]=M2(i*4+h) [16..19]=c2 [20..35]=M3 [36..39]=c3
//                       [40..43]=M4 [44]=c4
// ---------------------------------------------------------------------------
#define AMB ((NN + 255) / 256)  // 79

__global__ void aux_kernel(const int* __restrict__ row_ptr, const uint2* __restrict__ attr_pk,
                           float* __restrict__ mean_attr, const int* __restrict__ batch,
                           int* __restrict__ bound, const float* __restrict__ We_enc,
                           const float* __restrict__ be_enc, const float* __restrict__ We2,
                           const float* __restrict__ ae2, const float* __restrict__ We3,
                           const float* __restrict__ ae3, const float* __restrict__ We4,
                           const float* __restrict__ ae4, float* __restrict__ fold) {
  int b = blockIdx.x;
  int t = threadIdx.x;
  if (b < AMB) {
    int node = b * 256 + t;
    if (node < NN) {
      int p0 = row_ptr[node], p1 = row_ptr[node + 1];
      float s0 = 0.f, s1 = 0.f, s2 = 0.f, s3 = 0.f;
      for (int p = p0; p < p1; ++p) {
        uint2 q = attr_pk[p];
        s0 += bf_lo(q.x); s1 += bf_hi(q.x);
        s2 += bf_lo(q.y); s3 += bf_hi(q.y);
      }
      int deg = p1 - p0;
      float inv = 1.f / (float)(deg > 1 ? deg : 1);
      ((float4*)mean_attr)[node] = make_float4(s0 * inv, s1 * inv, s2 * inv, s3 * inv);
    }
    return;
  }
  if (b < 2 * AMB) {
    int i = (b - AMB) * 256 + t;
    if (i >= NN) return;
    int bc = batch[i];
    int bp = (i == 0) ? -1 : batch[i - 1];
    for (int g = bp + 1; g <= bc; ++g) bound[g] = i;
    if (i == NN - 1)
      for (int g = bc + 1; g <= GG; ++g) bound[g] = NN;
    return;
  }
  __shared__ float V[32 * 4];
  if (t < 128) {
    int k = t >> 2, h = t & 3;
    float s = 0.f;
    for (int c = 0; c < 32; ++c) s = fmaf(We2[k * 128 + h * 32 + c], ae2[h * 32 + c], s);
    V[k * 4 + h] = s;
  }
  __syncthreads();
  if (t < 16) {
    int i = t >> 2, h = t & 3;
    float s = 0.f;
    for (int k = 0; k < 32; ++k) s = fmaf(We_enc[i * 32 + k], V[k * 4 + h], s);
    fold[i * 4 + h] = s;
  } else if (t < 20) {
    int h = t - 16;
    float s = 0.f;
    for (int k = 0; k < 32; ++k) s = fmaf(be_enc[k], V[k * 4 + h], s);
    fold[16 + h] = s;
  }
  __syncthreads();
  if (t < 128) {
    int k = t >> 2, h = t & 3;
    float s = 0.f;
    for (int c = 0; c < 32; ++c) s = fmaf(We3[k * 128 + h * 32 + c], ae3[h * 32 + c], s);
    V[k * 4 + h] = s;
  }
  __syncthreads();
  if (t < 16) {
    int i = t >> 2, h = t & 3;
    float s = 0.f;
    for (int k = 0; k < 32; ++k) s = fmaf(We_enc[i * 32 + k], V[k * 4 + h], s);
    fold[20 + i * 4 + h] = s;
  } else if (t < 20) {
    int h = t - 16;
    float s = 0.f;
    for (int k = 0; k < 32; ++k) s = fmaf(be_enc[k], V[k * 4 + h], s);
    fold[36 + h] = s;
  }
  __syncthreads();
  if (t < 32) {
    float s = 0.f;
    for (int c = 0; c < 32; ++c) s = fmaf(We4[t * 32 + c], ae4[c], s);
    V[t] = s;
  }
  __syncthreads();
  if (t < 4) {
    float s = 0.f;
    for (int k = 0; k < 32; ++k) s = fmaf(We_enc[t * 32 + k], V[k], s);
    fold[40 + t] = s;
  } else if (t == 4) {
    float s = 0.f;
    for (int k = 0; k < 32; ++k) s = fmaf(be_enc[k], V[k], s);
    fold[44] = s;
  }
}

// ---------------------------------------------------------------------------
// Node GEMM v2 (K=128): register-tiled TRx4, W staged in LDS as bf16,
// X tile fp32 in LDS. Fused a_s/a_d head reductions.
// ---------------------------------------------------------------------------
template <int COLS, int TR>
__global__ __launch_bounds__(256) void gemm2_kernel(const float* __restrict__ X,
                                                    const float* __restrict__ W,
                                                    const float* __restrict__ att_s,
                                                    const float* __restrict__ att_d,
                                                    __hip_bfloat16* __restrict__ H,
                                                    float* __restrict__ a_s,
                                                    float* __restrict__ a_d) {
  constexpr int K = 128;
  constexpr int HEADS = COLS / 32;
  constexpr int CG = COLS / 4;   // col-groups (4 cols each)
  constexpr int RG = 256 / CG;   // row-groups
  constexpr int ROWS = RG * TR;  // rows per block
  __shared__ unsigned short ws[K * COLS];  // bf16 bits, [k][c]
  __shared__ float xs[ROWS * K];           // [r][k]
  int tid = threadIdx.x;
  int row0 = blockIdx.x * ROWS;
  for (int i = tid * 4; i < K * COLS; i += 1024) {
    float4 wv = *(const float4*)&W[i];
    ushort4 u;
    u.x = f2bf(wv.x); u.y = f2bf(wv.y); u.z = f2bf(wv.z); u.w = f2bf(wv.w);
    *(ushort4*)&ws[i] = u;
  }
  for (int i = tid * 4; i < ROWS * K; i += 1024) {
    int grow = row0 + i / K;
    float4 v = make_float4(0.f, 0.f, 0.f, 0.f);
    if (grow < NN) v = *(const float4*)&X[(size_t)grow * K + (i & (K - 1))];
    *(float4*)&xs[i] = v;
  }
  __syncthreads();
  int cg = tid % CG, rg = tid / CG;
  int c0 = cg * 4, r0 = rg * TR;
  float acc[TR][4];
#pragma unroll
  for (int i = 0; i < TR; ++i)
#pragma unroll
    for (int j = 0; j < 4; ++j) acc[i][j] = 0.f;
  for (int k0 = 0; k0 < K; k0 += 4) {
    float w4[4][4];
#pragma unroll
    for (int j = 0; j < 4; ++j) {
      ushort4 u = *(ushort4*)&ws[(k0 + j) * COLS + c0];
      w4[j][0] = bf2f(u.x); w4[j][1] = bf2f(u.y); w4[j][2] = bf2f(u.z); w4[j][3] = bf2f(u.w);
    }
#pragma unroll
    for (int i = 0; i < TR; ++i) {
      float4 xv = *(float4*)&xs[(r0 + i) * K + k0];
#pragma unroll
      for (int j = 0; j < 4; ++j) {
        acc[i][j] = fmaf(xv.x, w4[0][j], acc[i][j]);
        acc[i][j] = fmaf(xv.y, w4[1][j], acc[i][j]);
        acc[i][j] = fmaf(xv.z, w4[2][j], acc[i][j]);
        acc[i][j] = fmaf(xv.w, w4[3][j], acc[i][j]);
      }
    }
  }
  float as4[4], ad4[4];
#pragma unroll
  for (int j = 0; j < 4; ++j) { as4[j] = att_s[c0 + j]; ad4[j] = att_d[c0 + j]; }
  int h = c0 >> 5;
#pragma unroll
  for (int i = 0; i < TR; ++i) {
    int row = row0 + r0 + i;
    ushort4 hv;
    hv.x = f2bf(acc[i][0]); hv.y = f2bf(acc[i][1]); hv.z = f2bf(acc[i][2]); hv.w = f2bf(acc[i][3]);
    if (row < NN) *(ushort4*)&H[(size_t)row * COLS + c0] = hv;
    float vs = 0.f, vd = 0.f;
#pragma unroll
    for (int j = 0; j < 4; ++j) {
      vs = fmaf(acc[i][j], as4[j], vs);
      vd = fmaf(acc[i][j], ad4[j], vd);
    }
#pragma unroll
    for (int m = 1; m <= 4; m <<= 1) {
      vs += __shfl_xor(vs, m);
      vd += __shfl_xor(vd, m);
    }
    if ((tid & 7) == 0 && row < NN) {
      a_s[row * HEADS + h] = vs;
      a_d[row * HEADS + h] = vd;
    }
  }
}

// ---------------------------------------------------------------------------
// GAT aggregation v5: alphas once per edge-head; exp weights + src indices
// stashed in wave-local LDS (linear conflict-free writes, broadcast reads with
// immediate offsets — no bpermute in the gather loop). Branchless softmax.
// ---------------------------------------------------------------------------
template <int HEADS, bool RELU, bool HAS_EDGE>
__global__ __launch_bounds__(256) void gat_agg5_kernel(
    const __hip_bfloat16* __restrict__ Hh, const float* __restrict__ a_s,
    const float* __restrict__ a_d, const uint2* __restrict__ attr_pk,
    const float* __restrict__ mean_attr, const float* __restrict__ foldM,
    const float* __restrict__ foldC, const int* __restrict__ row_ptr,
    const int* __restrict__ csr_src, const float* __restrict__ bias,
    float* __restrict__ out) {
  constexpr int COLS = HEADS * 32;
  constexpr int NL = COLS / 2;     // lanes per node: 64 (H=4) or 16 (H=1)
  constexpr int NPB = 256 / NL;    // nodes per block: 4 or 16
  constexpr int EPP = 16;          // edges per register slot
  constexpr int JMAX = CAP / EPP;  // 6
  constexpr int EXS = CAP * HEADS + (HEADS == 1 ? 1 : 0);  // pad H=1 vs bank alias
  constexpr int SRS = CAP + (HEADS == 1 ? 1 : 0);

  __shared__ float ex_lds[NPB][EXS];
  __shared__ int src_lds[NPB][SRS];

  int tid = threadIdx.x;
  int ln = tid % NL;
  int nl = tid / NL;
  int node = blockIdx.x * NPB + nl;  // grids exact: NN%4==0, NN%16==0
  int p0 = row_ptr[node], p1 = row_ptr[node + 1];
  int deg = p1 - p0;
  int base = (tid & 63) & ~(NL - 1);  // node's base lane within wave
  const uint32* H32 = (const uint32*)Hh;
  int c = 2 * ln;
  int hc = (HEADS == 4) ? (c >> 5) : 0;

  if (deg > CAP) {
    // ---- slow fallback (never taken for this input; formal correctness) ----
    float gm0 = 0.f, gm1 = 0.f, gm2 = 0.f, gm3 = 0.f, gc = 0.f;
    if (HAS_EDGE) {
      if (HEADS == 4) {
        gm0 = foldM[hc]; gm1 = foldM[4 + hc]; gm2 = foldM[8 + hc]; gm3 = foldM[12 + hc];
        gc = foldC[hc];
      } else {
        gm0 = foldM[0]; gm1 = foldM[1]; gm2 = foldM[2]; gm3 = foldM[3];
        gc = foldC[0];
      }
    }
    float adv = a_d[node * HEADS + hc];
    float al = a_s[node * HEADS + hc] + adv;
    if (HAS_EDGE) {
      float4 m4 = ((const float4*)mean_attr)[node];
      al += fmaf(m4.x, gm0, fmaf(m4.y, gm1, fmaf(m4.z, gm2, fmaf(m4.w, gm3, gc))));
    }
    al = al >= 0.f ? al : 0.2f * al;
    float m = al;
    for (int p = p0; p < p1; ++p) {
      int s = csr_src[p];
      float a = a_s[s * HEADS + hc] + adv;
      if (HAS_EDGE) {
        uint2 q = attr_pk[p];
        a += fmaf(bf_lo(q.x), gm0,
                  fmaf(bf_hi(q.x), gm1, fmaf(bf_lo(q.y), gm2, fmaf(bf_hi(q.y), gm3, gc))));
      }
      a = a >= 0.f ? a : 0.2f * a;
      m = fmaxf(m, a);
    }
    float e0 = __expf(al - m);
    float den = e0;
    uint32 u0 = H32[(size_t)node * NL + ln];
    float acc0 = e0 * bf_lo(u0), acc1 = e0 * bf_hi(u0);
    for (int p = p0; p < p1; ++p) {
      int s = csr_src[p];
      float a = a_s[s * HEADS + hc] + adv;
      if (HAS_EDGE) {
        uint2 q = attr_pk[p];
        a += fmaf(bf_lo(q.x), gm0,
                  fmaf(bf_hi(q.x), gm1, fmaf(bf_lo(q.y), gm2, fmaf(bf_hi(q.y), gm3, gc))));
      }
      a = a >= 0.f ? a : 0.2f * a;
      float ex = __expf(a - m);
      den += ex;
      uint32 u = H32[(size_t)s * NL + ln];
      acc0 = fmaf(ex, bf_lo(u), acc0);
      acc1 = fmaf(ex, bf_hi(u), acc1);
    }
    float inv = 1.f / (den + 1e-16f);
    float o0 = acc0 * inv + bias[c];
    float o1 = acc1 * inv + bias[c + 1];
    if (RELU) { o0 = fmaxf(o0, 0.f); o1 = fmaxf(o1, 0.f); }
    *(float2*)&out[(size_t)node * COLS + c] = make_float2(o0, o1);
    return;
  }

  int p_rel = ln / HEADS;  // 0..15
  int h = ln % HEADS;
  float adv = a_d[node * HEADS + h];
  float fm0 = 0.f, fm1 = 0.f, fm2 = 0.f, fm3 = 0.f, fc = 0.f;
  if (HAS_EDGE) {
    if (HEADS == 4) {
      fm0 = foldM[h]; fm1 = foldM[4 + h]; fm2 = foldM[8 + h]; fm3 = foldM[12 + h];
      fc = foldC[h];
    } else {
      fm0 = foldM[0]; fm1 = foldM[1]; fm2 = foldM[2]; fm3 = foldM[3];
      fc = foldC[0];
    }
  }

  // ---- Phase A: alphas (once per edge-head), src stash, running max
  float av[JMAX];
  float mpart = -1e30f;
#pragma unroll
  for (int j = 0; j < JMAX; ++j) {
    int pr = p_rel + j * EPP;
    av[j] = -1e30f;
    int s = 0;
    if (pr < deg) {
      int p = p0 + pr;
      s = csr_src[p];
      float a = a_s[s * HEADS + h] + adv;
      if (HAS_EDGE) {
        uint2 q = attr_pk[p];
        a += fmaf(bf_lo(q.x), fm0,
                  fmaf(bf_hi(q.x), fm1, fmaf(bf_lo(q.y), fm2, fmaf(bf_hi(q.y), fm3, fc))));
      }
      a = a >= 0.f ? a : 0.2f * a;
      av[j] = a;
      mpart = fmaxf(mpart, a);
    }
    if (HEADS == 1 || h == 0) src_lds[nl][pr] = s;  // s=0 for invalid slots
  }
  float al = -1e30f;
  if (p_rel == 0) {
    al = a_s[node * HEADS + h] + adv;
    if (HAS_EDGE && deg > 0) {
      float4 m4 = ((const float4*)mean_attr)[node];
      al += fmaf(m4.x, fm0, fmaf(m4.y, fm1, fmaf(m4.z, fm2, fmaf(m4.w, fm3, fc))));
    }
    al = al >= 0.f ? al : 0.2f * al;
    mpart = fmaxf(mpart, al);
  }
  float mfull = mpart;
#pragma unroll
  for (int m = HEADS; m < NL; m <<= 1) mfull = fmaxf(mfull, __shfl_xor(mfull, m));

  // ---- Phase B: branchless exp, stash weights, denominator
  float dpart = 0.f;
#pragma unroll
  for (int j = 0; j < JMAX; ++j) {
    int pr = p_rel + j * EPP;
    float ex = __expf(av[j] - mfull);  // 0 for invalid slots
    ex_lds[nl][pr * HEADS + h] = ex;   // linear per wave: addr = ln + j*NL
    dpart += ex;
  }
  float exl = 0.f;
  if (p_rel == 0) {
    exl = __expf(al - mfull);
    dpart += exl;
  }
  float den = dpart;
#pragma unroll
  for (int m = HEADS; m < NL; m <<= 1) den += __shfl_xor(den, m);

  // ---- Phase C: weighted bf16 gather; LDS broadcast reads, imm offsets
  float exl_c = __shfl(exl, base + hc);
  float den_c = __shfl(den, base + hc);
  uint32 u0 = H32[(size_t)node * NL + ln];
  float acc0 = exl_c * bf_lo(u0);
  float acc1 = exl_c * bf_hi(u0);
#pragma unroll
  for (int j = 0; j < JMAX; ++j) {
    if (j * EPP < deg) {
      float exv[EPP];
      int sval[EPP];
#pragma unroll
      for (int pp = 0; pp < EPP; ++pp) {
        int p = j * EPP + pp;
        sval[pp] = src_lds[nl][p];            // same-addr broadcast
        exv[pp] = ex_lds[nl][p * HEADS + hc]; // 4-addr broadcast groups
      }
      uint32 uv[EPP];
#pragma unroll
      for (int pp = 0; pp < EPP; ++pp) uv[pp] = H32[(size_t)sval[pp] * NL + ln];
#pragma unroll
      for (int pp = 0; pp < EPP; ++pp) {
        acc0 = fmaf(exv[pp], bf_lo(uv[pp]), acc0);
        acc1 = fmaf(exv[pp], bf_hi(uv[pp]), acc1);
      }
    }
  }
  float inv = 1.f / (den_c + 1e-16f);
  float o0 = acc0 * inv + bias[c];
  float o1 = acc1 * inv + bias[c + 1];
  if (RELU) { o0 = fmaxf(o0, 0.f); o1 = fmaxf(o1, 0.f); }
  *(float2*)&out[(size_t)node * COLS + c] = make_float2(o0, o1);
}

// ---------------------------------------------------------------------------
// Fused mean-pool + descriptor MLP + final linear + sigmoid
// ---------------------------------------------------------------------------
__global__ void pool_final_kernel(const float* __restrict__ h4, const int* __restrict__ bound,
                                  const float* __restrict__ desc, const float* __restrict__ Wd,
                                  const float* __restrict__ bd, const float* __restrict__ Wl,
                                  const float* __restrict__ bl, float* __restrict__ outp) {
  __shared__ float part[8][32];
  int g = blockIdx.x;
  int tid = threadIdx.x;  // 256
  int r0 = bound[g], r1 = bound[g + 1];
  int cch = tid & 31, chunk = tid >> 5;
  float s = 0.f;
  for (int r = r0 + chunk; r < r1; r += 8) s += h4[r * 32 + cch];
  part[chunk][cch] = s;
  __syncthreads();
  if (tid < 64) {
    float v;
    if (tid < 32) {
      float tot = 0.f;
#pragma unroll
      for (int k = 0; k < 8; ++k) tot += part[k][tid];
      int rows = r1 - r0;
      float cnt = (float)(rows > 1 ? rows : 1);
      v = (tot / cnt) * Wl[tid];
    } else {
      int cc = tid - 32;
      float acc = bd[cc];
      for (int k = 0; k < 48; ++k) acc = fmaf(desc[g * 48 + k], Wd[k * 32 + cc], acc);
      v = fmaxf(acc, 0.f) * Wl[32 + cc];
    }
#pragma unroll
    for (int m = 32; m >= 1; m >>= 1) v += __shfl_xor(v, m);
    if (tid == 0) outp[g] = 1.f / (1.f + expf(-(v + bl[0])));
  }
}

// ---------------------------------------------------------------------------
extern "C" void kernel_launch(void* const* d_in, const int* in_sizes, int n_in,
                              void* d_out, int out_size, void* d_ws, size_t ws_size,
                              hipStream_t stream) {
  const float* x = (const float*)d_in[0];
  const int* ei = (const int*)d_in[1];
  const float* edge_attr = (const float*)d_in[2];
  const int* batch = (const int*)d_in[3];
  const float* desc = (const float*)d_in[4];
  const float* We_enc = (const float*)d_in[5];
  const float* be_enc = (const float*)d_in[6];
  const float* W1 = (const float*)d_in[7];
  const float* as1 = (const float*)d_in[8];
  const float* ad1 = (const float*)d_in[9];
  const float* b1 = (const float*)d_in[10];
  const float* W2 = (const float*)d_in[11];
  const float* We2 = (const float*)d_in[12];
  const float* as2 = (const float*)d_in[13];
  const float* ad2 = (const float*)d_in[14];
  const float* ae2 = (const float*)d_in[15];
  const float* b2 = (const float*)d_in[16];
  const float* W3 = (const float*)d_in[17];
  const float* We3 = (const float*)d_in[18];
  const float* as3 = (const float*)d_in[19];
  const float* ad3 = (const float*)d_in[20];
  const float* ae3 = (const float*)d_in[21];
  const float* b3 = (const float*)d_in[22];
  const float* W4 = (const float*)d_in[23];
  const float* We4 = (const float*)d_in[24];
  const float* as4 = (const float*)d_in[25];
  const float* ad4 = (const float*)d_in[26];
  const float* ae4 = (const float*)d_in[27];
  const float* b4 = (const float*)d_in[28];
  const float* Wd = (const float*)d_in[29];
  const float* bd = (const float*)d_in[30];
  const float* Wl = (const float*)d_in[31];
  const float* bl = (const float*)d_in[32];

  const int* srcp = ei;
  const int* dstp = ei + EE;

  char* w = (char*)d_ws;
  size_t off = 0;
  auto take = [&](size_t nbytes) -> void* {
    void* p = (void*)(w + off);
    off += (nbytes + 255) & ~(size_t)255;
    return p;
  };
  int* cnt = (int*)take(2 * NN * 4);  // [cnt | pos], zeroed in one memset
  int* pos = cnt + NN;
  int* row_ptr = (int*)take((NN + 1) * 4);
  int* csr_src = (int*)take((size_t)EE * 4);
  uint2* attr_pk = (uint2*)take((size_t)EE * 8);
  float* mean_attr = (float*)take(NN * 16);
  float* fold = (float*)take(48 * 4);
  int* partial = (int*)take(64 * 4);
  int* bound = (int*)take((GG + 1) * 4);
  float* a_s = (float*)take(NN * 16);
  float* a_d = (float*)take(NN * 16);
  __hip_bfloat16* hbuf = (__hip_bfloat16*)take((size_t)NN * 128 * 2);
  float* obuf = (float*)take((size_t)NN * 128 * 4);
  (void)ws_size;

  // ---- CSR build + layer-1 GEMM (fused) + aux
  hipMemsetAsync(cnt, 0, 2 * NN * 4, stream);
  histgemm1_kernel<<<HB + GB, 256, 0, stream>>>(dstp, cnt, x, W1, as1, ad1, hbuf, a_s, a_d);
  scan1_kernel<<<NSCAN, 1024, 0, stream>>>(cnt, row_ptr, partial);
  scan23_kernel<<<(NN + 256) / 256, 256, 0, stream>>>(row_ptr, partial);
  scatter_kernel<<<(EE + 255) / 256, 256, 0, stream>>>(srcp, dstp, edge_attr, row_ptr, pos,
                                                       csr_src, attr_pk);
  aux_kernel<<<2 * AMB + 1, 256, 0, stream>>>(row_ptr, attr_pk, mean_attr, batch, bound, We_enc,
                                              be_enc, We2, ae2, We3, ae3, We4, ae4, fold);

  // ---- layer 1 aggregation (no edge feats)
  gat_agg5_kernel<4, true, false><<<NN / 4, 256, 0, stream>>>(
      hbuf, a_s, a_d, nullptr, nullptr, nullptr, nullptr, row_ptr, csr_src, b1, obuf);
  // ---- layer 2
  gemm2_kernel<128, 4><<<NN / 32, 256, 0, stream>>>(obuf, W2, as2, ad2, hbuf, a_s, a_d);
  gat_agg5_kernel<4, true, true><<<NN / 4, 256, 0, stream>>>(
      hbuf, a_s, a_d, attr_pk, mean_attr, fold + 0, fold + 16, row_ptr, csr_src, b2, obuf);
  // ---- layer 3
  gemm2_kernel<128, 4><<<NN / 32, 256, 0, stream>>>(obuf, W3, as3, ad3, hbuf, a_s, a_d);
  gat_agg5_kernel<4, true, true><<<NN / 4, 256, 0, stream>>>(
      hbuf, a_s, a_d, attr_pk, mean_attr, fold + 20, fold + 36, row_ptr, csr_src, b3, obuf);
  // ---- layer 4 (128 -> 32, heads=1, no relu)
  gemm2_kernel<32, 2><<<(NN + 63) / 64, 256, 0, stream>>>(obuf, W4, as4, ad4, hbuf, a_s, a_d);
  gat_agg5_kernel<1, false, true><<<NN / 16, 256, 0, stream>>>(
      hbuf, a_s, a_d, attr_pk, mean_attr, fold + 40, fold + 44, row_ptr, csr_src, b4, obuf);

  // ---- fused pool + descriptor MLP + final linear + sigmoid
  pool_final_kernel<<<GG, 256, 0, stream>>>(obuf, bound, desc, Wd, bd, Wl, bl, (float*)d_out);
}

// Round 15
// 328.259 us; speedup vs baseline: 2.5156x; 1.0106x over previous
//
#include <hip/hip_runtime.h>
#include <hip/hip_bf16.h>
#include <math.h>

#define NN 20000
#define EE 480000
#define GG 200
#define CAP 96  // fast-path max degree (true max deg ~55); fallback is correct anyway

typedef unsigned int uint32;

static __device__ inline unsigned short f2bf(float f) {
  __hip_bfloat16 h = __float2bfloat16(f);
  return *reinterpret_cast<const unsigned short*>(&h);
}
static __device__ inline float bf2f(unsigned short u) {
  return __uint_as_float(((uint32)u) << 16);
}
static __device__ inline float bf_lo(uint32 u) { return __uint_as_float(u << 16); }
static __device__ inline float bf_hi(uint32 u) { return __uint_as_float(u & 0xffff0000u); }
static __device__ inline uint32 pack2(float lo, float hi) {
  return ((uint32)f2bf(lo)) | (((uint32)f2bf(hi)) << 16);
}

#define HB ((EE + 255) / 256)   // 1875 hist blocks
#define GB (NN / 16)            // 1250 gemm1 blocks
#define AMB ((NN + 255) / 256)  // 79
#define NSCAN ((NN + 1023) / 1024)  // 20

// ---------------------------------------------------------------------------
// Fused hist + gemm1 + bound + fold: blocks [0,HB) histogram dst;
// [HB,HB+GB) layer-1 GEMM; [HB+GB,HB+GB+AMB) graph bounds; last block fold.
// ---------------------------------------------------------------------------
__global__ void histgemm1_kernel(const int* __restrict__ dst, int* __restrict__ cnt,
                                 const float* __restrict__ X, const float* __restrict__ W,
                                 const float* __restrict__ att_s, const float* __restrict__ att_d,
                                 __hip_bfloat16* __restrict__ H, float* __restrict__ a_s,
                                 float* __restrict__ a_d, const int* __restrict__ batch,
                                 int* __restrict__ bound, const float* __restrict__ We_enc,
                                 const float* __restrict__ be_enc, const float* __restrict__ We2,
                                 const float* __restrict__ ae2, const float* __restrict__ We3,
                                 const float* __restrict__ ae3, const float* __restrict__ We4,
                                 const float* __restrict__ ae4, float* __restrict__ fold) {
  int tid = threadIdx.x;
  int b = blockIdx.x;
  if (b < HB) {
    int i = b * 256 + tid;
    if (i < EE) atomicAdd(&cnt[dst[i]], 1);
    return;
  }
  if (b < HB + GB) {
    __shared__ float xs[16][8];
    int row0 = (b - HB) * 16;
    if (tid < 128) xs[tid >> 3][tid & 7] = X[row0 * 8 + tid];
    __syncthreads();
    int c = tid & 127;
    int half = tid >> 7;  // rows [8*half, 8*half+8)
    float acc[8];
#pragma unroll
    for (int j = 0; j < 8; ++j) acc[j] = 0.f;
    for (int k = 0; k < 8; ++k) {
      float wv = W[k * 128 + c];
#pragma unroll
      for (int j = 0; j < 8; ++j) acc[j] = fmaf(xs[half * 8 + j][k], wv, acc[j]);
    }
    float asv = att_s[c], adv = att_d[c];
#pragma unroll
    for (int j = 0; j < 8; ++j) {
      int row = row0 + half * 8 + j;
      float vs = acc[j] * asv, vd = acc[j] * adv;
#pragma unroll
      for (int m = 16; m >= 1; m >>= 1) {
        vs += __shfl_xor(vs, m);
        vd += __shfl_xor(vd, m);
      }
      H[row * 128 + c] = __float2bfloat16(acc[j]);
      if ((tid & 31) == 0) {
        a_s[row * 4 + (c >> 5)] = vs;
        a_d[row * 4 + (c >> 5)] = vd;
      }
    }
    return;
  }
  if (b < HB + GB + AMB) {
    // ---- graph boundaries (batch sorted)
    int i = (b - HB - GB) * 256 + tid;
    if (i >= NN) return;
    int bc = batch[i];
    int bp = (i == 0) ? -1 : batch[i - 1];
    for (int g = bp + 1; g <= bc; ++g) bound[g] = i;
    if (i == NN - 1)
      for (int g = bc + 1; g <= GG; ++g) bound[g] = NN;
    return;
  }
  // ---- fold constants (compute guarded to subsets of threads, barriers not)
  __shared__ float V[32 * 4];
  int t = tid;
  if (t < 128) {
    int k = t >> 2, h = t & 3;
    float s = 0.f;
    for (int c = 0; c < 32; ++c) s = fmaf(We2[k * 128 + h * 32 + c], ae2[h * 32 + c], s);
    V[k * 4 + h] = s;
  }
  __syncthreads();
  if (t < 16) {
    int i = t >> 2, h = t & 3;
    float s = 0.f;
    for (int k = 0; k < 32; ++k) s = fmaf(We_enc[i * 32 + k], V[k * 4 + h], s);
    fold[i * 4 + h] = s;
  } else if (t < 20) {
    int h = t - 16;
    float s = 0.f;
    for (int k = 0; k < 32; ++k) s = fmaf(be_enc[k], V[k * 4 + h], s);
    fold[16 + h] = s;
  }
  __syncthreads();
  if (t < 128) {
    int k = t >> 2, h = t & 3;
    float s = 0.f;
    for (int c = 0; c < 32; ++c) s = fmaf(We3[k * 128 + h * 32 + c], ae3[h * 32 + c], s);
    V[k * 4 + h] = s;
  }
  __syncthreads();
  if (t < 16) {
    int i = t >> 2, h = t & 3;
    float s = 0.f;
    for (int k = 0; k < 32; ++k) s = fmaf(We_enc[i * 32 + k], V[k * 4 + h], s);
    fold[20 + i * 4 + h] = s;
  } else if (t < 20) {
    int h = t - 16;
    float s = 0.f;
    for (int k = 0; k < 32; ++k) s = fmaf(be_enc[k], V[k * 4 + h], s);
    fold[36 + h] = s;
  }
  __syncthreads();
  if (t < 32) {
    float s = 0.f;
    for (int c = 0; c < 32; ++c) s = fmaf(We4[t * 32 + c], ae4[c], s);
    V[t] = s;
  }
  __syncthreads();
  if (t < 4) {
    float s = 0.f;
    for (int k = 0; k < 32; ++k) s = fmaf(We_enc[t * 32 + k], V[k], s);
    fold[40 + t] = s;
  } else if (t == 4) {
    float s = 0.f;
    for (int k = 0; k < 32; ++k) s = fmaf(be_enc[k], V[k], s);
    fold[44] = s;
  }
}

// ---------------------------------------------------------------------------
// CSR build: multi-block scan, scatter
// ---------------------------------------------------------------------------
__global__ void scan1_kernel(const int* __restrict__ cnt, int* __restrict__ row_ptr,
                             int* __restrict__ partial) {
  __shared__ int buf[1024];
  int t = threadIdx.x;
  int i = blockIdx.x * 1024 + t;
  int v = (i < NN) ? cnt[i] : 0;
  buf[t] = v;
  __syncthreads();
  for (int offd = 1; offd < 1024; offd <<= 1) {
    int tmp = (t >= offd) ? buf[t - offd] : 0;
    __syncthreads();
    buf[t] += tmp;
    __syncthreads();
  }
  if (i < NN) row_ptr[i + 1] = buf[t];  // inclusive within block
  if (t == 1023) partial[blockIdx.x] = buf[1023];
}

__global__ void scan23_kernel(int* __restrict__ row_ptr, const int* __restrict__ partial) {
  __shared__ int sc[NSCAN];
  int t = threadIdx.x;
  if (t < 64) {
    int v = (t < NSCAN) ? partial[t] : 0;
    for (int o = 1; o < 32; o <<= 1) {
      int u = __shfl_up(v, o);
      if (t >= o) v += u;
    }
    if (t < NSCAN) sc[t] = v;  // inclusive scan of partials
  }
  __syncthreads();
  int i = blockIdx.x * 256 + t;
  if (i == 0) row_ptr[0] = 0;
  if (i >= 1 && i <= NN) {
    int b = (i - 1) >> 10;
    if (b > 0) row_ptr[i] += sc[b - 1];
  }
}

__global__ void scatter_kernel(const int* __restrict__ src, const int* __restrict__ dst,
                               const float* __restrict__ attr, const int* __restrict__ row_ptr,
                               int* __restrict__ pos, int* __restrict__ csr_src,
                               uint2* __restrict__ attr_pk) {
  int e = blockIdx.x * 256 + threadIdx.x;
  if (e >= EE) return;
  int d = dst[e];
  int p = row_ptr[d] + atomicAdd(&pos[d], 1);
  csr_src[p] = src[e];
  float4 a = ((const float4*)attr)[e];
  uint2 q;
  q.x = pack2(a.x, a.y);
  q.y = pack2(a.z, a.w);
  attr_pk[p] = q;
}

// ---------------------------------------------------------------------------
// Node GEMM v2 (K=128): register-tiled TRx4, W staged in LDS as bf16,
// X tile fp32 in LDS. Fused a_s/a_d head reductions.
// ---------------------------------------------------------------------------
template <int COLS, int TR>
__global__ __launch_bounds__(256) void gemm2_kernel(const float* __restrict__ X,
                                                    const float* __restrict__ W,
                                                    const float* __restrict__ att_s,
                                                    const float* __restrict__ att_d,
                                                    __hip_bfloat16* __restrict__ H,
                                                    float* __restrict__ a_s,
                                                    float* __restrict__ a_d) {
  constexpr int K = 128;
  constexpr int HEADS = COLS / 32;
  constexpr int CG = COLS / 4;   // col-groups (4 cols each)
  constexpr int RG = 256 / CG;   // row-groups
  constexpr int ROWS = RG * TR;  // rows per block
  __shared__ unsigned short ws[K * COLS];  // bf16 bits, [k][c]
  __shared__ float xs[ROWS * K];           // [r][k]
  int tid = threadIdx.x;
  int row0 = blockIdx.x * ROWS;
  for (int i = tid * 4; i < K * COLS; i += 1024) {
    float4 wv = *(const float4*)&W[i];
    ushort4 u;
    u.x = f2bf(wv.x); u.y = f2bf(wv.y); u.z = f2bf(wv.z); u.w = f2bf(wv.w);
    *(ushort4*)&ws[i] = u;
  }
  for (int i = tid * 4; i < ROWS * K; i += 1024) {
    int grow = row0 + i / K;
    float4 v = make_float4(0.f, 0.f, 0.f, 0.f);
    if (grow < NN) v = *(const float4*)&X[(size_t)grow * K + (i & (K - 1))];
    *(float4*)&xs[i] = v;
  }
  __syncthreads();
  int cg = tid % CG, rg = tid / CG;
  int c0 = cg * 4, r0 = rg * TR;
  float acc[TR][4];
#pragma unroll
  for (int i = 0; i < TR; ++i)
#pragma unroll
    for (int j = 0; j < 4; ++j) acc[i][j] = 0.f;
  for (int k0 = 0; k0 < K; k0 += 4) {
    float w4[4][4];
#pragma unroll
    for (int j = 0; j < 4; ++j) {
      ushort4 u = *(ushort4*)&ws[(k0 + j) * COLS + c0];
      w4[j][0] = bf2f(u.x); w4[j][1] = bf2f(u.y); w4[j][2] = bf2f(u.z); w4[j][3] = bf2f(u.w);
    }
#pragma unroll
    for (int i = 0; i < TR; ++i) {
      float4 xv = *(float4*)&xs[(r0 + i) * K + k0];
#pragma unroll
      for (int j = 0; j < 4; ++j) {
        acc[i][j] = fmaf(xv.x, w4[0][j], acc[i][j]);
        acc[i][j] = fmaf(xv.y, w4[1][j], acc[i][j]);
        acc[i][j] = fmaf(xv.z, w4[2][j], acc[i][j]);
        acc[i][j] = fmaf(xv.w, w4[3][j], acc[i][j]);
      }
    }
  }
  float as4[4], ad4[4];
#pragma unroll
  for (int j = 0; j < 4; ++j) { as4[j] = att_s[c0 + j]; ad4[j] = att_d[c0 + j]; }
  int h = c0 >> 5;
#pragma unroll
  for (int i = 0; i < TR; ++i) {
    int row = row0 + r0 + i;
    ushort4 hv;
    hv.x = f2bf(acc[i][0]); hv.y = f2bf(acc[i][1]); hv.z = f2bf(acc[i][2]); hv.w = f2bf(acc[i][3]);
    if (row < NN) *(ushort4*)&H[(size_t)row * COLS + c0] = hv;
    float vs = 0.f, vd = 0.f;
#pragma unroll
    for (int j = 0; j < 4; ++j) {
      vs = fmaf(acc[i][j], as4[j], vs);
      vd = fmaf(acc[i][j], ad4[j], vd);
    }
#pragma unroll
    for (int m = 1; m <= 4; m <<= 1) {
      vs += __shfl_xor(vs, m);
      vd += __shfl_xor(vd, m);
    }
    if ((tid & 7) == 0 && row < NN) {
      a_s[row * HEADS + h] = vs;
      a_d[row * HEADS + h] = vd;
    }
  }
}

// ---------------------------------------------------------------------------
// GAT aggregation v6: Phase-A load hoisting (csr_src+attr_pk first, then a_s
// gathers, then ALU); exp weights + src indices in wave-local LDS; branchless
// softmax. AMEAN: extra blocks past NN/NPB compute per-node attr means.
// ---------------------------------------------------------------------------
template <int HEADS, bool RELU, bool HAS_EDGE, bool AMEAN>
__global__ __launch_bounds__(256) void gat_agg6_kernel(
    const __hip_bfloat16* __restrict__ Hh, const float* __restrict__ a_s,
    const float* __restrict__ a_d, const uint2* __restrict__ attr_pk,
    float* __restrict__ mean_attr, const float* __restrict__ foldM,
    const float* __restrict__ foldC, const int* __restrict__ row_ptr,
    const int* __restrict__ csr_src, const float* __restrict__ bias,
    float* __restrict__ out) {
  constexpr int COLS = HEADS * 32;
  constexpr int NL = COLS / 2;     // lanes per node: 64 (H=4) or 16 (H=1)
  constexpr int NPB = 256 / NL;    // nodes per block: 4 or 16
  constexpr int EPP = 16;          // edges per register slot
  constexpr int JMAX = CAP / EPP;  // 6
  constexpr int EXS = CAP * HEADS + (HEADS == 1 ? 1 : 0);  // pad H=1 vs bank alias
  constexpr int SRS = CAP + (HEADS == 1 ? 1 : 0);
  constexpr int NB = NN / NPB;

  __shared__ float ex_lds[NPB][EXS];
  __shared__ int src_lds[NPB][SRS];

  int tid = threadIdx.x;
  if (AMEAN && blockIdx.x >= NB) {
    // ---- per-node attr mean (fused aux work; runs concurrently with agg)
    int node = (blockIdx.x - NB) * 256 + tid;
    if (node < NN) {
      int p0 = row_ptr[node], p1 = row_ptr[node + 1];
      float s0 = 0.f, s1 = 0.f, s2 = 0.f, s3 = 0.f;
      for (int p = p0; p < p1; ++p) {
        uint2 q = attr_pk[p];
        s0 += bf_lo(q.x); s1 += bf_hi(q.x);
        s2 += bf_lo(q.y); s3 += bf_hi(q.y);
      }
      int deg = p1 - p0;
      float inv = 1.f / (float)(deg > 1 ? deg : 1);
      ((float4*)mean_attr)[node] = make_float4(s0 * inv, s1 * inv, s2 * inv, s3 * inv);
    }
    return;
  }

  int ln = tid % NL;
  int nl = tid / NL;
  int node = blockIdx.x * NPB + nl;  // grids exact: NN%4==0, NN%16==0
  int p0 = row_ptr[node], p1 = row_ptr[node + 1];
  int deg = p1 - p0;
  int base = (tid & 63) & ~(NL - 1);  // node's base lane within wave
  const uint32* H32 = (const uint32*)Hh;
  int c = 2 * ln;
  int hc = (HEADS == 4) ? (c >> 5) : 0;

  if (deg > CAP) {
    // ---- slow fallback (never taken for this input; formal correctness) ----
    float gm0 = 0.f, gm1 = 0.f, gm2 = 0.f, gm3 = 0.f, gc = 0.f;
    if (HAS_EDGE) {
      if (HEADS == 4) {
        gm0 = foldM[hc]; gm1 = foldM[4 + hc]; gm2 = foldM[8 + hc]; gm3 = foldM[12 + hc];
        gc = foldC[hc];
      } else {
        gm0 = foldM[0]; gm1 = foldM[1]; gm2 = foldM[2]; gm3 = foldM[3];
        gc = foldC[0];
      }
    }
    float adv = a_d[node * HEADS + hc];
    float al = a_s[node * HEADS + hc] + adv;
    if (HAS_EDGE) {
      float4 m4 = ((const float4*)mean_attr)[node];
      al += fmaf(m4.x, gm0, fmaf(m4.y, gm1, fmaf(m4.z, gm2, fmaf(m4.w, gm3, gc))));
    }
    al = al >= 0.f ? al : 0.2f * al;
    float m = al;
    for (int p = p0; p < p1; ++p) {
      int s = csr_src[p];
      float a = a_s[s * HEADS + hc] + adv;
      if (HAS_EDGE) {
        uint2 q = attr_pk[p];
        a += fmaf(bf_lo(q.x), gm0,
                  fmaf(bf_hi(q.x), gm1, fmaf(bf_lo(q.y), gm2, fmaf(bf_hi(q.y), gm3, gc))));
      }
      a = a >= 0.f ? a : 0.2f * a;
      m = fmaxf(m, a);
    }
    float e0 = __expf(al - m);
    float den = e0;
    uint32 u0 = H32[(size_t)node * NL + ln];
    float acc0 = e0 * bf_lo(u0), acc1 = e0 * bf_hi(u0);
    for (int p = p0; p < p1; ++p) {
      int s = csr_src[p];
      float a = a_s[s * HEADS + hc] + adv;
      if (HAS_EDGE) {
        uint2 q = attr_pk[p];
        a += fmaf(bf_lo(q.x), gm0,
                  fmaf(bf_hi(q.x), gm1, fmaf(bf_lo(q.y), gm2, fmaf(bf_hi(q.y), gm3, gc))));
      }
      a = a >= 0.f ? a : 0.2f * a;
      float ex = __expf(a - m);
      den += ex;
      uint32 u = H32[(size_t)s * NL + ln];
      acc0 = fmaf(ex, bf_lo(u), acc0);
      acc1 = fmaf(ex, bf_hi(u), acc1);
    }
    float inv = 1.f / (den + 1e-16f);
    float o0 = acc0 * inv + bias[c];
    float o1 = acc1 * inv + bias[c + 1];
    if (RELU) { o0 = fmaxf(o0, 0.f); o1 = fmaxf(o1, 0.f); }
    *(float2*)&out[(size_t)node * COLS + c] = make_float2(o0, o1);
    return;
  }

  int p_rel = ln / HEADS;  // 0..15
  int h = ln % HEADS;
  float adv = a_d[node * HEADS + h];
  float fm0 = 0.f, fm1 = 0.f, fm2 = 0.f, fm3 = 0.f, fc = 0.f;
  if (HAS_EDGE) {
    if (HEADS == 4) {
      fm0 = foldM[h]; fm1 = foldM[4 + h]; fm2 = foldM[8 + h]; fm3 = foldM[12 + h];
      fc = foldC[h];
    } else {
      fm0 = foldM[0]; fm1 = foldM[1]; fm2 = foldM[2]; fm3 = foldM[3];
      fc = foldC[0];
    }
  }

  // ---- Phase A1: issue ALL index + attr loads (independent, deep MLP)
  int sv[JMAX];
  uint2 qv[JMAX];
#pragma unroll
  for (int j = 0; j < JMAX; ++j) {
    int pr = p_rel + j * EPP;
    sv[j] = 0;
    if (HAS_EDGE) qv[j] = make_uint2(0u, 0u);
    if (pr < deg) {
      int p = p0 + pr;
      sv[j] = csr_src[p];
      if (HAS_EDGE) qv[j] = attr_pk[p];
    }
    if (HEADS == 1 || h == 0) src_lds[nl][pr] = sv[j];  // 0 for invalid slots
  }
  // ---- Phase A2: issue ALL a_s gathers
  float asv[JMAX];
#pragma unroll
  for (int j = 0; j < JMAX; ++j) {
    int pr = p_rel + j * EPP;
    asv[j] = (pr < deg) ? a_s[sv[j] * HEADS + h] : 0.f;
  }
  // ---- Phase A3: alphas + running max
  float av[JMAX];
  float mpart = -1e30f;
#pragma unroll
  for (int j = 0; j < JMAX; ++j) {
    int pr = p_rel + j * EPP;
    av[j] = -1e30f;
    if (pr < deg) {
      float a = asv[j] + adv;
      if (HAS_EDGE) {
        uint2 q = qv[j];
        a += fmaf(bf_lo(q.x), fm0,
                  fmaf(bf_hi(q.x), fm1, fmaf(bf_lo(q.y), fm2, fmaf(bf_hi(q.y), fm3, fc))));
      }
      a = a >= 0.f ? a : 0.2f * a;
      av[j] = a;
      mpart = fmaxf(mpart, a);
    }
  }
  float al = -1e30f;
  if (p_rel == 0) {
    al = a_s[node * HEADS + h] + adv;
    if (HAS_EDGE && deg > 0) {
      float4 m4 = ((const float4*)mean_attr)[node];
      al += fmaf(m4.x, fm0, fmaf(m4.y, fm1, fmaf(m4.z, fm2, fmaf(m4.w, fm3, fc))));
    }
    al = al >= 0.f ? al : 0.2f * al;
    mpart = fmaxf(mpart, al);
  }
  float mfull = mpart;
#pragma unroll
  for (int m = HEADS; m < NL; m <<= 1) mfull = fmaxf(mfull, __shfl_xor(mfull, m));

  // ---- Phase B: branchless exp, stash weights, denominator
  float dpart = 0.f;
#pragma unroll
  for (int j = 0; j < JMAX; ++j) {
    int pr = p_rel + j * EPP;
    float ex = __expf(av[j] - mfull);  // 0 for invalid slots
    ex_lds[nl][pr * HEADS + h] = ex;   // linear per wave: addr = ln + j*NL
    dpart += ex;
  }
  float exl = 0.f;
  if (p_rel == 0) {
    exl = __expf(al - mfull);
    dpart += exl;
  }
  float den = dpart;
#pragma unroll
  for (int m = HEADS; m < NL; m <<= 1) den += __shfl_xor(den, m);

  // ---- Phase C: weighted bf16 gather; LDS broadcast reads, imm offsets
  float exl_c = __shfl(exl, base + hc);
  float den_c = __shfl(den, base + hc);
  uint32 u0 = H32[(size_t)node * NL + ln];
  float acc0 = exl_c * bf_lo(u0);
  float acc1 = exl_c * bf_hi(u0);
#pragma unroll
  for (int j = 0; j < JMAX; ++j) {
    if (j * EPP < deg) {
      float exv[EPP];
      int sval[EPP];
#pragma unroll
      for (int pp = 0; pp < EPP; ++pp) {
        int p = j * EPP + pp;
        sval[pp] = src_lds[nl][p];            // same-addr broadcast
        exv[pp] = ex_lds[nl][p * HEADS + hc]; // 4-addr broadcast groups
      }
      uint32 uv[EPP];
#pragma unroll
      for (int pp = 0; pp < EPP; ++pp) uv[pp] = H32[(size_t)sval[pp] * NL + ln];
#pragma unroll
      for (int pp = 0; pp < EPP; ++pp) {
        acc0 = fmaf(exv[pp], bf_lo(uv[pp]), acc0);
        acc1 = fmaf(exv[pp], bf_hi(uv[pp]), acc1);
      }
    }
  }
  float inv = 1.f / (den_c + 1e-16f);
  float o0 = acc0 * inv + bias[c];
  float o1 = acc1 * inv + bias[c + 1];
  if (RELU) { o0 = fmaxf(o0, 0.f); o1 = fmaxf(o1, 0.f); }
  *(float2*)&out[(size_t)node * COLS + c] = make_float2(o0, o1);
}

// ---------------------------------------------------------------------------
// Fused mean-pool + descriptor MLP + final linear + sigmoid
// ---------------------------------------------------------------------------
__global__ void pool_final_kernel(const float* __restrict__ h4, const int* __restrict__ bound,
                                  const float* __restrict__ desc, const float* __restrict__ Wd,
                                  const float* __restrict__ bd, const float* __restrict__ Wl,
                                  const float* __restrict__ bl, float* __restrict__ outp) {
  __shared__ float part[8][32];
  int g = blockIdx.x;
  int tid = threadIdx.x;  // 256
  int r0 = bound[g], r1 = bound[g + 1];
  int cch = tid & 31, chunk = tid >> 5;
  float s = 0.f;
  for (int r = r0 + chunk; r < r1; r += 8) s += h4[r * 32 + cch];
  part[chunk][cch] = s;
  __syncthreads();
  if (tid < 64) {
    float v;
    if (tid < 32) {
      float tot = 0.f;
#pragma unroll
      for (int k = 0; k < 8; ++k) tot += part[k][tid];
      int rows = r1 - r0;
      float cnt = (float)(rows > 1 ? rows : 1);
      v = (tot / cnt) * Wl[tid];
    } else {
      int cc = tid - 32;
      float acc = bd[cc];
      for (int k = 0; k < 48; ++k) acc = fmaf(desc[g * 48 + k], Wd[k * 32 + cc], acc);
      v = fmaxf(acc, 0.f) * Wl[32 + cc];
    }
#pragma unroll
    for (int m = 32; m >= 1; m >>= 1) v += __shfl_xor(v, m);
    if (tid == 0) outp[g] = 1.f / (1.f + expf(-(v + bl[0])));
  }
}

// ---------------------------------------------------------------------------
extern "C" void kernel_launch(void* const* d_in, const int* in_sizes, int n_in,
                              void* d_out, int out_size, void* d_ws, size_t ws_size,
                              hipStream_t stream) {
  const float* x = (const float*)d_in[0];
  const int* ei = (const int*)d_in[1];
  const float* edge_attr = (const float*)d_in[2];
  const int* batch = (const int*)d_in[3];
  const float* desc = (const float*)d_in[4];
  const float* We_enc = (const float*)d_in[5];
  const float* be_enc = (const float*)d_in[6];
  const float* W1 = (const float*)d_in[7];
  const float* as1 = (const float*)d_in[8];
  const float* ad1 = (const float*)d_in[9];
  const float* b1 = (const float*)d_in[10];
  const float* W2 = (const float*)d_in[11];
  const float* We2 = (const float*)d_in[12];
  const float* as2 = (const float*)d_in[13];
  const float* ad2 = (const float*)d_in[14];
  const float* ae2 = (const float*)d_in[15];
  const float* b2 = (const float*)d_in[16];
  const float* W3 = (const float*)d_in[17];
  const float* We3 = (const float*)d_in[18];
  const float* as3 = (const float*)d_in[19];
  const float* ad3 = (const float*)d_in[20];
  const float* ae3 = (const float*)d_in[21];
  const float* b3 = (const float*)d_in[22];
  const float* W4 = (const float*)d_in[23];
  const float* We4 = (const float*)d_in[24];
  const float* as4 = (const float*)d_in[25];
  const float* ad4 = (const float*)d_in[26];
  const float* ae4 = (const float*)d_in[27];
  const float* b4 = (const float*)d_in[28];
  const float* Wd = (const float*)d_in[29];
  const float* bd = (const float*)d_in[30];
  const float* Wl = (const float*)d_in[31];
  const float* bl = (const float*)d_in[32];

  const int* srcp = ei;
  const int* dstp = ei + EE;

  char* w = (char*)d_ws;
  size_t off = 0;
  auto take = [&](size_t nbytes) -> void* {
    void* p = (void*)(w + off);
    off += (nbytes + 255) & ~(size_t)255;
    return p;
  };
  int* cnt = (int*)take(2 * NN * 4);  // [cnt | pos], zeroed in one memset
  int* pos = cnt + NN;
  int* row_ptr = (int*)take((NN + 1) * 4);
  int* csr_src = (int*)take((size_t)EE * 4);
  uint2* attr_pk = (uint2*)take((size_t)EE * 8);
  float* mean_attr = (float*)take(NN * 16);
  float* fold = (float*)take(48 * 4);
  int* partial = (int*)take(64 * 4);
  int* bound = (int*)take((GG + 1) * 4);
  float* a_s = (float*)take(NN * 16);
  float* a_d = (float*)take(NN * 16);
  __hip_bfloat16* hbuf = (__hip_bfloat16*)take((size_t)NN * 128 * 2);
  float* obuf = (float*)take((size_t)NN * 128 * 4);
  (void)ws_size;

  // ---- CSR build + layer-1 GEMM + bounds + fold (all fused)
  hipMemsetAsync(cnt, 0, 2 * NN * 4, stream);
  histgemm1_kernel<<<HB + GB + AMB + 1, 256, 0, stream>>>(
      dstp, cnt, x, W1, as1, ad1, hbuf, a_s, a_d, batch, bound, We_enc, be_enc, We2, ae2, We3,
      ae3, We4, ae4, fold);
  scan1_kernel<<<NSCAN, 1024, 0, stream>>>(cnt, row_ptr, partial);
  scan23_kernel<<<(NN + 256) / 256, 256, 0, stream>>>(row_ptr, partial);
  scatter_kernel<<<(EE + 255) / 256, 256, 0, stream>>>(srcp, dstp, edge_attr, row_ptr, pos,
                                                       csr_src, attr_pk);

  // ---- layer 1 aggregation (no edge feats) + fused attr-mean blocks
  gat_agg6_kernel<4, true, false, true><<<NN / 4 + AMB, 256, 0, stream>>>(
      hbuf, a_s, a_d, attr_pk, mean_attr, nullptr, nullptr, row_ptr, csr_src, b1, obuf);
  // ---- layer 2
  gemm2_kernel<128, 4><<<NN / 32, 256, 0, stream>>>(obuf, W2, as2, ad2, hbuf, a_s, a_d);
  gat_agg6_kernel<4, true, true, false><<<NN / 4, 256, 0, stream>>>(
      hbuf, a_s, a_d, attr_pk, mean_attr, fold + 0, fold + 16, row_ptr, csr_src, b2, obuf);
  // ---- layer 3
  gemm2_kernel<128, 4><<<NN / 32, 256, 0, stream>>>(obuf, W3, as3, ad3, hbuf, a_s, a_d);
  gat_agg6_kernel<4, true, true, false><<<NN / 4, 256, 0, stream>>>(
      hbuf, a_s, a_d, attr_pk, mean_attr, fold + 20, fold + 36, row_ptr, csr_src, b3, obuf);
  // ---- layer 4 (128 -> 32, heads=1, no relu)
  gemm2_kernel<32, 2><<<(NN + 63) / 64, 256, 0, stream>>>(obuf, W4, as4, ad4, hbuf, a_s, a_d);
  gat_agg6_kernel<1, false, true, false><<<NN / 16, 256, 0, stream>>>(
      hbuf, a_s, a_d, attr_pk, mean_attr, fold + 40, fold + 44, row_ptr, csr_src, b4, obuf);

  // ---- fused pool + descriptor MLP + final linear + sigmoid
  pool_final_kernel<<<GG, 256, 0, stream>>>(obuf, bound, desc, Wd, bd, Wl, bl, (float*)d_out);
}